// Round 11
// baseline (359.205 us; speedup 1.0000x reference)
//
#include <hip/hip_runtime.h>
#include <hip/hip_bf16.h>

#define B_  4
#define S_  2048
#define D_  1024
#define H_  16
#define DH  64
#define M_  (B_ * S_)   // 8192

typedef unsigned short u16;
typedef unsigned int u32;
typedef __attribute__((ext_vector_type(8))) short bf16x8;
typedef __attribute__((ext_vector_type(4))) float f32x4;
typedef __attribute__((ext_vector_type(4))) unsigned short u16x4;
typedef __attribute__((ext_vector_type(4))) unsigned int u32x4;

static __device__ __forceinline__ u16 f2bf(float x) {
    union { float f; unsigned u; } c;
    c.f = x;
    const unsigned u = c.u;
    return (u16)((u + 0x7FFFu + ((u >> 16) & 1u)) >> 16);
}
static __device__ __forceinline__ float bf2f(u16 h) {
    union { unsigned u; float f; } c;
    c.u = ((unsigned)h) << 16;
    return c.f;
}
#ifdef __BF16_MANT_DIG__
static __device__ __forceinline__ u16 f2bf_hw(float x) {
    __bf16 b = (__bf16)x;
    return __builtin_bit_cast(u16, b);
}
#else
#define f2bf_hw f2bf
#endif
#if __has_builtin(__builtin_amdgcn_exp2f)
#define fexp2 __builtin_amdgcn_exp2f
#else
#define fexp2 exp2f
#endif
// async 16B global->LDS (LDS dest = wave-uniform base + lane*16)
static __device__ __forceinline__ void gl16(const u16* g, u16* l) {
    __builtin_amdgcn_global_load_lds(
        (const __attribute__((address_space(1))) unsigned int*)g,
        (__attribute__((address_space(3))) unsigned int*)l, 16, 0, 0);
}
// v_cvt_pk_bf16_f32: dst.lo16=bf16(a), dst.hi16=bf16(b)
static __device__ __forceinline__ u32 cvtpk(float a, float b) {
    u32 r;
    asm("v_cvt_pk_bf16_f32 %0, %1, %2" : "=v"(r) : "v"(a), "v"(b));
    return r;
}
// swap d[32:63] <-> s[0:31]
static __device__ __forceinline__ void pswap32(u32& d, u32& s) {
    asm volatile("v_permlane32_swap_b32 %0, %1" : "+v"(d), "+v"(s));
}
// swap d[16:31]<->s[0:15], d[48:63]<->s[32:47]
static __device__ __forceinline__ void pswap16(u32& d, u32& s) {
    asm volatile("v_permlane16_swap_b32 %0, %1" : "+v"(d), "+v"(s));
}

// ---------------------------------------------------------------------------
// Fused prep: cast x,wq,wk,wv -> bf16; split wo -> hi/lo bf16. One launch.
// ---------------------------------------------------------------------------
__global__ __launch_bounds__(256) void prep(const float* __restrict__ x,
                                            const float* __restrict__ wq,
                                            const float* __restrict__ wk,
                                            const float* __restrict__ wv,
                                            const float* __restrict__ wo,
                                            u16* __restrict__ xh,
                                            u16* __restrict__ wh,   // 3 blocks
                                            u16* __restrict__ woh,
                                            u16* __restrict__ wol) {
    const size_t NX = (size_t)M_ * D_ / 4;  // 2097152
    const size_t NW = (size_t)D_ * D_ / 4;  // 262144
    const size_t i = (size_t)blockIdx.x * 256 + threadIdx.x;
    if (i < NX) {
        float4 v = ((const float4*)x)[i];
        u16x4 h;
        h[0] = f2bf_hw(v.x); h[1] = f2bf_hw(v.y);
        h[2] = f2bf_hw(v.z); h[3] = f2bf_hw(v.w);
        ((u16x4*)xh)[i] = h;
    } else if (i < NX + 3 * NW) {
        const size_t j = i - NX;
        const int sel = (int)(j / NW);
        const size_t k = j - (size_t)sel * NW;
        const float* src = sel == 0 ? wq : sel == 1 ? wk : wv;
        float4 v = ((const float4*)src)[k];
        u16x4 h;
        h[0] = f2bf_hw(v.x); h[1] = f2bf_hw(v.y);
        h[2] = f2bf_hw(v.z); h[3] = f2bf_hw(v.w);
        ((u16x4*)(wh + (size_t)sel * D_ * D_))[k] = h;
    } else {
        const size_t k = i - NX - 3 * NW;
        float4 v = ((const float4*)wo)[k];
        u16x4 h, l;
        float vv[4] = {v.x, v.y, v.z, v.w};
#pragma unroll
        for (int j = 0; j < 4; ++j) {
            h[j] = f2bf_hw(vv[j]);
            l[j] = f2bf_hw(vv[j] - bf2f(h[j]));
        }
        ((u16x4*)woh)[k] = h;
        ((u16x4*)wol)[k] = l;
    }
}

// ---------------------------------------------------------------------------
// Merged QKV GEMM: {Q,K,V} = x @ W{q,k,v}^T + b, 1-pass bf16, double-buffered
// (1 barrier/K-step). 256x128 tile, 8 waves. Grid 768, XCD-chunked.
// ---------------------------------------------------------------------------
__global__ __launch_bounds__(512) void gemm_qkv(const u16* __restrict__ xh,
                                                const u16* __restrict__ whb,
                                                const float* __restrict__ bq,
                                                const float* __restrict__ bk,
                                                const float* __restrict__ bv,
                                                u16* __restrict__ qb,
                                                u16* __restrict__ kb,
                                                u16* __restrict__ vt) {
    __shared__ __align__(16) u16 sA[2 * 8192];  // [buf][256 rows][32 cols]
    __shared__ __align__(16) u16 sB[2 * 4096];  // [buf][128 rows][32 cols]

    const int tid = threadIdx.x;
    const int l = tid & 63;
    const int w = tid >> 6;      // 0..7
    const int lo = l & 15;
    const int hi = l >> 4;
    const int wr = w >> 1;       // 0..3 quadrant row
    const int wc = w & 1;        // 0..1 quadrant col
    const int L = blockIdx.x;
    const int c = L & 7;
    const int t = L >> 3;            // 0..95
    const int by = c * 4 + (t & 3);  // 0..31
    const int bxs = t >> 2;          // 0..23
    const int wsel = bxs >> 3;       // 0..2
    const int bx = bxs & 7;          // 0..7
    const int m0 = by * 256;
    const int n0 = bx * 128;

    const u16* W = whb + (size_t)wsel * D_ * D_;
    const float* bias = wsel == 0 ? bq : wsel == 1 ? bk : bv;

    auto stage = [&](int k0, int buf) {
#pragma unroll
        for (int i = 0; i < 2; ++i) {       // A: 1024 slots / 512 thr
            const int p = 512 * i + tid;
            const int row = p >> 2;          // 0..255
            const int ps = p & 3;
            const int sl = ps ^ ((row + (row >> 2)) & 3);
            const int lb = buf * 8192 + (512 * i + 64 * w) * 8;
            gl16(xh + (size_t)(m0 + row) * D_ + k0 + 8 * sl, &sA[lb]);
        }
        {                                    // B: 512 slots / 512 thr
            const int p = tid;
            const int row = p >> 2;          // 0..127
            const int ps = p & 3;
            const int sl = ps ^ ((row + (row >> 2)) & 3);
            const int lb = buf * 4096 + (64 * w) * 8;
            gl16(W + (size_t)(n0 + row) * D_ + k0 + 8 * sl, &sB[lb]);
        }
    };

    const f32x4 z4 = {0.f, 0.f, 0.f, 0.f};
    f32x4 acc[4][4];
#pragma unroll
    for (int i = 0; i < 4; ++i)
#pragma unroll
        for (int j = 0; j < 4; ++j) acc[i][j] = z4;

    stage(0, 0);
    for (int k0 = 0; k0 < D_; k0 += 32) {
        const int cur = (k0 >> 5) & 1;
        __syncthreads();  // drains prefetched loads; closes prev reads
        if (k0 + 32 < D_) stage(k0 + 32, cur ^ 1);

        bf16x8 ah[4], bh[4];
#pragma unroll
        for (int mi = 0; mi < 4; ++mi) {
            const int r = wr * 64 + mi * 16 + lo;
            const int sl = hi ^ ((r + (r >> 2)) & 3);
            ah[mi] = *(const bf16x8*)&sA[cur * 8192 + r * 32 + sl * 8];
        }
#pragma unroll
        for (int nj = 0; nj < 4; ++nj) {
            const int r = wc * 64 + nj * 16 + lo;
            const int sl = hi ^ ((r + (r >> 2)) & 3);
            bh[nj] = *(const bf16x8*)&sB[cur * 4096 + r * 32 + sl * 8];
        }
#pragma unroll
        for (int mi = 0; mi < 4; ++mi)
#pragma unroll
            for (int nj = 0; nj < 4; ++nj)
                acc[mi][nj] = __builtin_amdgcn_mfma_f32_16x16x32_bf16(
                    ah[mi], bh[nj], acc[mi][nj], 0, 0, 0);
    }

    float bv_[4];
#pragma unroll
    for (int nj = 0; nj < 4; ++nj) bv_[nj] = bias[n0 + wc * 64 + nj * 16 + lo];

#pragma unroll
    for (int mi = 0; mi < 4; ++mi)
#pragma unroll
        for (int nj = 0; nj < 4; ++nj)
#pragma unroll
            for (int r = 0; r < 4; ++r) {
                const float v = acc[mi][nj][r] + bv_[nj];
                const int cm = m0 + wr * 64 + mi * 16 + hi * 4 + r;
                const int cn = n0 + wc * 64 + nj * 16 + lo;
                const int b = cm >> 11, s = cm & (S_ - 1);
                const int h = cn >> 6, d = cn & 63;
                if (wsel == 0)  // fold 0.125 * log2(e) for log2-domain softmax
                    qb[(((size_t)b * H_ + h) * S_ + s) * DH + d] =
                        f2bf(v * 0.18033688011112042f);
                else if (wsel == 1)
                    kb[(((size_t)b * H_ + h) * S_ + s) * DH + d] = f2bf(v);
                else
                    vt[(((size_t)b * H_ + h) * DH + d) * S_ + s] = f2bf(v);
            }
}

// ---------------------------------------------------------------------------
// Final GEMM: out = ctx @ wo^T + bo, 3-pass split-bf16, fp32 output.
// Double-buffered (1 barrier/K-step), 64KB LDS.
// ---------------------------------------------------------------------------
__global__ __launch_bounds__(256) void gemm_out(const u16* __restrict__ Ah,
                                                const u16* __restrict__ Al,
                                                const u16* __restrict__ Wh,
                                                const u16* __restrict__ Wl,
                                                const float* __restrict__ bias,
                                                float* __restrict__ Cout) {
    __shared__ __align__(16) u16 sAh[8192];
    __shared__ __align__(16) u16 sBh[8192];
    __shared__ __align__(16) u16 sAl[8192];
    __shared__ __align__(16) u16 sBl[8192];

    const int tid = threadIdx.x;
    const int l = tid & 63;
    const int w = tid >> 6;
    const int lo = l & 15;
    const int hi = l >> 4;
    const int wr = w >> 1;
    const int wc = w & 1;
    const int L = blockIdx.x;
    const int c = L & 7;
    const int t = L >> 3;
    const int by = c * 8 + (t >> 3);
    const int bx = t & 7;
    const int m0 = by * 128;
    const int n0 = bx * 128;

    auto stage = [&](int k0, int half) {
#pragma unroll
        for (int i = 0; i < 2; ++i) {
            const int p = 256 * i + tid;
            const int row = p >> 2;
            const int ps = p & 3;
            const int sl = ps ^ ((row + (row >> 2)) & 3);
            const int lb = half * 4096 + (256 * i + 64 * w) * 8;
            const size_t ga = (size_t)(m0 + row) * D_ + k0 + 8 * sl;
            const size_t gb = (size_t)(n0 + row) * D_ + k0 + 8 * sl;
            gl16(Ah + ga, &sAh[lb]);
            gl16(Al + ga, &sAl[lb]);
            gl16(Wh + gb, &sBh[lb]);
            gl16(Wl + gb, &sBl[lb]);
        }
    };

    const f32x4 z4 = {0.f, 0.f, 0.f, 0.f};
    f32x4 acc[4][4];
#pragma unroll
    for (int i = 0; i < 4; ++i)
#pragma unroll
        for (int j = 0; j < 4; ++j) acc[i][j] = z4;

    stage(0, 0);
    for (int k0 = 0; k0 < D_; k0 += 32) {
        const int cur = (k0 >> 5) & 1;
        __syncthreads();  // drains prefetched loads; closes prev reads
        if (k0 + 32 < D_) stage(k0 + 32, cur ^ 1);
        const int bufo = cur * 4096;

        bf16x8 ah[4], al_[4], bh[4], bl_[4];
#pragma unroll
        for (int mi = 0; mi < 4; ++mi) {
            const int r = wr * 64 + mi * 16 + lo;
            const int sl = hi ^ ((r + (r >> 2)) & 3);
            ah[mi] = *(const bf16x8*)&sAh[bufo + r * 32 + sl * 8];
            al_[mi] = *(const bf16x8*)&sAl[bufo + r * 32 + sl * 8];
        }
#pragma unroll
        for (int nj = 0; nj < 4; ++nj) {
            const int r = wc * 64 + nj * 16 + lo;
            const int sl = hi ^ ((r + (r >> 2)) & 3);
            bh[nj] = *(const bf16x8*)&sBh[bufo + r * 32 + sl * 8];
            bl_[nj] = *(const bf16x8*)&sBl[bufo + r * 32 + sl * 8];
        }
#pragma unroll
        for (int mi = 0; mi < 4; ++mi)
#pragma unroll
            for (int nj = 0; nj < 4; ++nj) {
                acc[mi][nj] = __builtin_amdgcn_mfma_f32_16x16x32_bf16(
                    ah[mi], bh[nj], acc[mi][nj], 0, 0, 0);
                acc[mi][nj] = __builtin_amdgcn_mfma_f32_16x16x32_bf16(
                    ah[mi], bl_[nj], acc[mi][nj], 0, 0, 0);
                acc[mi][nj] = __builtin_amdgcn_mfma_f32_16x16x32_bf16(
                    al_[mi], bh[nj], acc[mi][nj], 0, 0, 0);
            }
    }

    float bv_[4];
#pragma unroll
    for (int nj = 0; nj < 4; ++nj) bv_[nj] = bias[n0 + wc * 64 + nj * 16 + lo];

#pragma unroll
    for (int mi = 0; mi < 4; ++mi)
#pragma unroll
        for (int nj = 0; nj < 4; ++nj)
#pragma unroll
            for (int r = 0; r < 4; ++r) {
                const int cm = m0 + wr * 64 + mi * 16 + hi * 4 + r;
                const int cn = n0 + wc * 64 + nj * 16 + lo;
                Cout[(size_t)cm * D_ + cn] = acc[mi][nj][r] + bv_[nj];
            }
}

// ---------------------------------------------------------------------------
// MFMA flash attention v7: K via LDS (gl16 dbuf), V-fragments read DIRECTLY
// from global/L2 (no V staging). Rationale: all 4 waves read identical K/V
// fragments; LDS b128 BW (~85B/cyc/CU) was saturated at 64KB/block-tile.
// Splitting V to the L2 pool (L2-resident via XCD mapping, 64B-coalesced,
// latency hidden under QK+softmax) halves LDS traffic. LDS 16KB.
// Fixed-max softmax + T12 cvt_pk/permlane in-register P transpose unchanged.
// ---------------------------------------------------------------------------
__global__ __launch_bounds__(256, 4) void attn7(const u16* __restrict__ Qb,
                                                const u16* __restrict__ Kb,
                                                const u16* __restrict__ Vtg,
                                                u16* __restrict__ chi,
                                                u16* __restrict__ clo) {
    __shared__ __align__(16) u16 KsA[2 * 4096];  // [buf][kv 64][d 64] swizzled

    const int tid = threadIdx.x;
    const int l = tid & 63;
    const int w = tid >> 6;
    const int lo = l & 15;
    const int hi = l >> 4;
    const int L = blockIdx.x;
    const int c = L & 7;
    const int t = L >> 3;             // 0..127
    const int bh = c * 8 + (t >> 4);  // 0..63
    const int s0 = (t & 15) * 128;
    const size_t base = (size_t)bh * S_ * DH;

    const int sp0 = tid;
    const int srow0 = sp0 >> 3, ssl0 = (sp0 & 7) ^ (srow0 & 7);
    const int sp1 = 256 + tid;
    const int srow1 = sp1 >> 3, ssl1 = (sp1 & 7) ^ (srow1 & 7);
    const int lb0 = (64 * w) * 8;
    const int lb1 = (256 + 64 * w) * 8;

    // Q fragments, 2 q-halves (pre-scaled by 0.125*log2e in the QKV epilogue)
    bf16x8 qa[2][2];
#pragma unroll
    for (int qh = 0; qh < 2; ++qh) {
        const u16* qp = Qb + base + (size_t)(s0 + w * 32 + qh * 16 + lo) * DH;
        qa[qh][0] = *(const bf16x8*)(qp + hi * 8);
        qa[qh][1] = *(const bf16x8*)(qp + hi * 8 + 32);
    }

    const f32x4 zero4 = {0.f, 0.f, 0.f, 0.f};
    f32x4 acc[2][4];
    f32x4 acc_l[2] = {zero4, zero4};
#pragma unroll
    for (int qh = 0; qh < 2; ++qh)
#pragma unroll
        for (int g = 0; g < 4; ++g) acc[qh][g] = zero4;

    const short onebf = (short)0x3F80;  // bf16 1.0
    const bf16x8 ones = {onebf, onebf, onebf, onebf, onebf, onebf, onebf, onebf};

    // per-lane V-fragment source rows (V^T [d][S]): d = lo+16g, col = hi*8+32ks
    const u16* vrow[4];
#pragma unroll
    for (int g = 0; g < 4; ++g)
        vrow[g] = Vtg + base + (size_t)(lo + 16 * g) * S_ + hi * 8;

#define STAGEK(KT, HALF)                                                       \
    do {                                                                       \
        const size_t kbase = base + (size_t)(KT) * 64 * DH;                    \
        gl16(Kb + kbase + (size_t)srow0 * DH + 8 * ssl0, &KsA[(HALF)*4096 + lb0]); \
        gl16(Kb + kbase + (size_t)srow1 * DH + 8 * ssl1, &KsA[(HALF)*4096 + lb1]); \
    } while (0)

    STAGEK(0, 0);

    for (int kt = 0; kt < S_ / 64; ++kt) {
        const int cur = kt & 1;
        __syncthreads();  // K tile kt staged; closes reads of buf cur^1
        if (kt + 1 < S_ / 64) STAGEK(kt + 1, cur ^ 1);
        const u16* Ks = &KsA[cur * 4096];

        // --- issue V-fragment loads for THIS tile (global/L2, no barrier dep);
        //     latency hides under QK^T + softmax.
        bf16x8 vf[4][2];
#pragma unroll
        for (int g = 0; g < 4; ++g) {
#pragma unroll
            for (int ks = 0; ks < 2; ++ks)
                vf[g][ks] = *(const bf16x8*)(vrow[g] + kt * 64 + 32 * ks);
        }

        // --- QK^T (swapped), K-frag shared across both q-halves
        f32x4 sc[2][4];
#pragma unroll
        for (int qh = 0; qh < 2; ++qh)
#pragma unroll
            for (int f = 0; f < 4; ++f) sc[qh][f] = zero4;
        __builtin_amdgcn_s_setprio(1);
#pragma unroll
        for (int f = 0; f < 4; ++f) {
            const int kr = lo + 16 * f;
            const int ksw = (kr & 7) << 3;
#pragma unroll
            for (int ks = 0; ks < 2; ++ks) {
                bf16x8 kf = *(const bf16x8*)&Ks[kr * 64 + ((hi * 8 + 32 * ks) ^ ksw)];
                sc[0][f] = __builtin_amdgcn_mfma_f32_16x16x32_bf16(kf, qa[0][ks], sc[0][f], 0, 0, 0);
                sc[1][f] = __builtin_amdgcn_mfma_f32_16x16x32_bf16(kf, qa[1][ks], sc[1][f], 0, 0, 0);
            }
        }
        __builtin_amdgcn_s_setprio(0);

        // --- p = exp2(sc); pack + permlane into PV A-fragments (no LDS)
        bf16x8 pa[2][2];
#pragma unroll
        for (int qh = 0; qh < 2; ++qh) {
            u32 T[2][4];
#pragma unroll
            for (int ks = 0; ks < 2; ++ks)
#pragma unroll
                for (int cc = 0; cc < 2; ++cc) {
                    u32 X = cvtpk(fexp2(sc[qh][2 * ks][2 * cc]),
                                  fexp2(sc[qh][2 * ks][2 * cc + 1]));
                    u32 Y = cvtpk(fexp2(sc[qh][2 * ks + 1][2 * cc]),
                                  fexp2(sc[qh][2 * ks + 1][2 * cc + 1]));
                    pswap32(X, Y);
                    pswap16(X, Y);
                    T[ks][cc] = X;
                    T[ks][2 + cc] = Y;
                }
#pragma unroll
            for (int ks = 0; ks < 2; ++ks) {
                u32x4 word = {T[ks][0], T[ks][1], T[ks][2], T[ks][3]};
                pa[qh][ks] = __builtin_bit_cast(bf16x8, word);
            }
        }

        // --- PV (swapped) + MFMA row-sum; V-frags now in registers
        __builtin_amdgcn_s_setprio(1);
        acc_l[0] = __builtin_amdgcn_mfma_f32_16x16x32_bf16(ones, pa[0][0], acc_l[0], 0, 0, 0);
        acc_l[0] = __builtin_amdgcn_mfma_f32_16x16x32_bf16(ones, pa[0][1], acc_l[0], 0, 0, 0);
        acc_l[1] = __builtin_amdgcn_mfma_f32_16x16x32_bf16(ones, pa[1][0], acc_l[1], 0, 0, 0);
        acc_l[1] = __builtin_amdgcn_mfma_f32_16x16x32_bf16(ones, pa[1][1], acc_l[1], 0, 0, 0);
#pragma unroll
        for (int g = 0; g < 4; ++g) {
#pragma unroll
            for (int ks = 0; ks < 2; ++ks) {
                acc[0][g] = __builtin_amdgcn_mfma_f32_16x16x32_bf16(vf[g][ks], pa[0][ks], acc[0][g], 0, 0, 0);
                acc[1][g] = __builtin_amdgcn_mfma_f32_16x16x32_bf16(vf[g][ks], pa[1][ks], acc[1][g], 0, 0, 0);
            }
        }
        __builtin_amdgcn_s_setprio(0);
    }
#undef STAGEK

    // epilogue: O[q][d] / l, split hi/lo bf16, u16x4 stores
    const int b = bh >> 4;
    const int h = bh & 15;
#pragma unroll
    for (int qh = 0; qh < 2; ++qh) {
        const float inv = 1.f / acc_l[qh][0];
        const int row = s0 + w * 32 + qh * 16 + lo;
#pragma unroll
        for (int g = 0; g < 4; ++g) {
            u16x4 hh, ll;
#pragma unroll
            for (int r = 0; r < 4; ++r) {
                const float v = acc[qh][g][r] * inv;
                hh[r] = f2bf_hw(v);
                ll[r] = f2bf_hw(v - bf2f(hh[r]));
            }
            const size_t off = ((size_t)b * S_ + row) * D_ + h * 64 + 16 * g + hi * 4;
            *(u16x4*)&chi[off] = hh;
            *(u16x4*)&clo[off] = ll;
        }
    }
}

// ---------------------------------------------------------------------------
extern "C" void kernel_launch(void* const* d_in, const int* in_sizes, int n_in,
                              void* d_out, int out_size, void* d_ws, size_t ws_size,
                              hipStream_t stream) {
    const float* x  = (const float*)d_in[0];
    const float* wq = (const float*)d_in[1];
    const float* bq = (const float*)d_in[2];
    const float* wk = (const float*)d_in[3];
    const float* bk = (const float*)d_in[4];
    const float* wv = (const float*)d_in[5];
    const float* bv = (const float*)d_in[6];
    const float* wo = (const float*)d_in[7];
    const float* bo = (const float*)d_in[8];
    float* out = (float*)d_out;

    const size_t MD = (size_t)M_ * D_;  // 8388608
    const size_t WD = (size_t)D_ * D_;  // 1048576
    u16* ws = (u16*)d_ws;
    u16* xh  = ws;             // MD
    u16* wh  = xh + MD;        // 3*WD (wq,wk,wv bf16)
    u16* woh = wh + 3 * WD;    // WD
    u16* wol = woh + WD;       // WD
    u16* qb  = wol + WD;       // MD
    u16* kb  = qb + MD;        // MD
    u16* vt  = kb + MD;        // MD
    u16* clo = vt + MD;        // MD
    u16* chi = xh;             // alias: x consumed by QKV GEMM before attn writes

    dim3 blk(256);
    // float4 work items: x 2M + 3 W casts 768K + wo split 256K = 3145728
    prep<<<dim3(12288), blk, 0, stream>>>(x, wq, wk, wv, wo, xh, wh, woh, wol);
    gemm_qkv<<<dim3(768), dim3(512), 0, stream>>>(xh, wh, bq, bk, bv, qb, kb, vt);
    attn7<<<dim3(1024), blk, 0, stream>>>(qb, kb, vt, chi, clo);
    gemm_out<<<dim3(512), blk, 0, stream>>>(chi, clo, woh, wol, bo, out);
}

// Round 12
// 224.079 us; speedup vs baseline: 1.6030x; 1.6030x over previous
//
#include <hip/hip_runtime.h>
#include <hip/hip_bf16.h>

#define B_  4
#define S_  2048
#define D_  1024
#define H_  16
#define DH  64
#define M_  (B_ * S_)   // 8192

typedef unsigned short u16;
typedef unsigned int u32;
typedef __attribute__((ext_vector_type(8))) short bf16x8;
typedef __attribute__((ext_vector_type(4))) float f32x4;
typedef __attribute__((ext_vector_type(4))) unsigned short u16x4;
typedef __attribute__((ext_vector_type(4))) unsigned int u32x4;

static __device__ __forceinline__ u16 f2bf(float x) {
    union { float f; unsigned u; } c;
    c.f = x;
    const unsigned u = c.u;
    return (u16)((u + 0x7FFFu + ((u >> 16) & 1u)) >> 16);
}
static __device__ __forceinline__ float bf2f(u16 h) {
    union { unsigned u; float f; } c;
    c.u = ((unsigned)h) << 16;
    return c.f;
}
#ifdef __BF16_MANT_DIG__
static __device__ __forceinline__ u16 f2bf_hw(float x) {
    __bf16 b = (__bf16)x;
    return __builtin_bit_cast(u16, b);
}
#else
#define f2bf_hw f2bf
#endif
#if __has_builtin(__builtin_amdgcn_exp2f)
#define fexp2 __builtin_amdgcn_exp2f
#else
#define fexp2 exp2f
#endif
// async 16B global->LDS (LDS dest = wave-uniform base + lane*16)
static __device__ __forceinline__ void gl16(const u16* g, u16* l) {
    __builtin_amdgcn_global_load_lds(
        (const __attribute__((address_space(1))) unsigned int*)g,
        (__attribute__((address_space(3))) unsigned int*)l, 16, 0, 0);
}
// v_cvt_pk_bf16_f32: dst.lo16=bf16(a), dst.hi16=bf16(b)
static __device__ __forceinline__ u32 cvtpk(float a, float b) {
    u32 r;
    asm("v_cvt_pk_bf16_f32 %0, %1, %2" : "=v"(r) : "v"(a), "v"(b));
    return r;
}
// swap d[32:63] <-> s[0:31]
static __device__ __forceinline__ void pswap32(u32& d, u32& s) {
    asm volatile("v_permlane32_swap_b32 %0, %1" : "+v"(d), "+v"(s));
}
// swap d[16:31]<->s[0:15], d[48:63]<->s[32:47]
static __device__ __forceinline__ void pswap16(u32& d, u32& s) {
    asm volatile("v_permlane16_swap_b32 %0, %1" : "+v"(d), "+v"(s));
}

// ---------------------------------------------------------------------------
// Fused prep: cast x,wq,wk,wv -> bf16; split wo -> hi/lo bf16. One launch.
// ---------------------------------------------------------------------------
__global__ __launch_bounds__(256) void prep(const float* __restrict__ x,
                                            const float* __restrict__ wq,
                                            const float* __restrict__ wk,
                                            const float* __restrict__ wv,
                                            const float* __restrict__ wo,
                                            u16* __restrict__ xh,
                                            u16* __restrict__ wh,   // 3 blocks
                                            u16* __restrict__ woh,
                                            u16* __restrict__ wol) {
    const size_t NX = (size_t)M_ * D_ / 4;  // 2097152
    const size_t NW = (size_t)D_ * D_ / 4;  // 262144
    const size_t i = (size_t)blockIdx.x * 256 + threadIdx.x;
    if (i < NX) {
        float4 v = ((const float4*)x)[i];
        u16x4 h;
        h[0] = f2bf_hw(v.x); h[1] = f2bf_hw(v.y);
        h[2] = f2bf_hw(v.z); h[3] = f2bf_hw(v.w);
        ((u16x4*)xh)[i] = h;
    } else if (i < NX + 3 * NW) {
        const size_t j = i - NX;
        const int sel = (int)(j / NW);
        const size_t k = j - (size_t)sel * NW;
        const float* src = sel == 0 ? wq : sel == 1 ? wk : wv;
        float4 v = ((const float4*)src)[k];
        u16x4 h;
        h[0] = f2bf_hw(v.x); h[1] = f2bf_hw(v.y);
        h[2] = f2bf_hw(v.z); h[3] = f2bf_hw(v.w);
        ((u16x4*)(wh + (size_t)sel * D_ * D_))[k] = h;
    } else {
        const size_t k = i - NX - 3 * NW;
        float4 v = ((const float4*)wo)[k];
        u16x4 h, l;
        float vv[4] = {v.x, v.y, v.z, v.w};
#pragma unroll
        for (int j = 0; j < 4; ++j) {
            h[j] = f2bf_hw(vv[j]);
            l[j] = f2bf_hw(vv[j] - bf2f(h[j]));
        }
        ((u16x4*)woh)[k] = h;
        ((u16x4*)wol)[k] = l;
    }
}

// ---------------------------------------------------------------------------
// Merged QKV GEMM: {Q,K,V} = x @ W{q,k,v}^T + b, 1-pass bf16, double-buffered
// (1 barrier/K-step). 256x128 tile, 8 waves. Grid 768, XCD-chunked.
// ---------------------------------------------------------------------------
__global__ __launch_bounds__(512) void gemm_qkv(const u16* __restrict__ xh,
                                                const u16* __restrict__ whb,
                                                const float* __restrict__ bq,
                                                const float* __restrict__ bk,
                                                const float* __restrict__ bv,
                                                u16* __restrict__ qb,
                                                u16* __restrict__ kb,
                                                u16* __restrict__ vt) {
    __shared__ __align__(16) u16 sA[2 * 8192];  // [buf][256 rows][32 cols]
    __shared__ __align__(16) u16 sB[2 * 4096];  // [buf][128 rows][32 cols]

    const int tid = threadIdx.x;
    const int l = tid & 63;
    const int w = tid >> 6;      // 0..7
    const int lo = l & 15;
    const int hi = l >> 4;
    const int wr = w >> 1;       // 0..3 quadrant row
    const int wc = w & 1;        // 0..1 quadrant col
    const int L = blockIdx.x;
    const int c = L & 7;
    const int t = L >> 3;            // 0..95
    const int by = c * 4 + (t & 3);  // 0..31
    const int bxs = t >> 2;          // 0..23
    const int wsel = bxs >> 3;       // 0..2
    const int bx = bxs & 7;          // 0..7
    const int m0 = by * 256;
    const int n0 = bx * 128;

    const u16* W = whb + (size_t)wsel * D_ * D_;
    const float* bias = wsel == 0 ? bq : wsel == 1 ? bk : bv;

    auto stage = [&](int k0, int buf) {
#pragma unroll
        for (int i = 0; i < 2; ++i) {       // A: 1024 slots / 512 thr
            const int p = 512 * i + tid;
            const int row = p >> 2;          // 0..255
            const int ps = p & 3;
            const int sl = ps ^ ((row + (row >> 2)) & 3);
            const int lb = buf * 8192 + (512 * i + 64 * w) * 8;
            gl16(xh + (size_t)(m0 + row) * D_ + k0 + 8 * sl, &sA[lb]);
        }
        {                                    // B: 512 slots / 512 thr
            const int p = tid;
            const int row = p >> 2;          // 0..127
            const int ps = p & 3;
            const int sl = ps ^ ((row + (row >> 2)) & 3);
            const int lb = buf * 4096 + (64 * w) * 8;
            gl16(W + (size_t)(n0 + row) * D_ + k0 + 8 * sl, &sB[lb]);
        }
    };

    const f32x4 z4 = {0.f, 0.f, 0.f, 0.f};
    f32x4 acc[4][4];
#pragma unroll
    for (int i = 0; i < 4; ++i)
#pragma unroll
        for (int j = 0; j < 4; ++j) acc[i][j] = z4;

    stage(0, 0);
    for (int k0 = 0; k0 < D_; k0 += 32) {
        const int cur = (k0 >> 5) & 1;
        __syncthreads();  // drains prefetched loads; closes prev reads
        if (k0 + 32 < D_) stage(k0 + 32, cur ^ 1);

        bf16x8 ah[4], bh[4];
#pragma unroll
        for (int mi = 0; mi < 4; ++mi) {
            const int r = wr * 64 + mi * 16 + lo;
            const int sl = hi ^ ((r + (r >> 2)) & 3);
            ah[mi] = *(const bf16x8*)&sA[cur * 8192 + r * 32 + sl * 8];
        }
#pragma unroll
        for (int nj = 0; nj < 4; ++nj) {
            const int r = wc * 64 + nj * 16 + lo;
            const int sl = hi ^ ((r + (r >> 2)) & 3);
            bh[nj] = *(const bf16x8*)&sB[cur * 4096 + r * 32 + sl * 8];
        }
#pragma unroll
        for (int mi = 0; mi < 4; ++mi)
#pragma unroll
            for (int nj = 0; nj < 4; ++nj)
                acc[mi][nj] = __builtin_amdgcn_mfma_f32_16x16x32_bf16(
                    ah[mi], bh[nj], acc[mi][nj], 0, 0, 0);
    }

    float bv_[4];
#pragma unroll
    for (int nj = 0; nj < 4; ++nj) bv_[nj] = bias[n0 + wc * 64 + nj * 16 + lo];

#pragma unroll
    for (int mi = 0; mi < 4; ++mi)
#pragma unroll
        for (int nj = 0; nj < 4; ++nj)
#pragma unroll
            for (int r = 0; r < 4; ++r) {
                const float v = acc[mi][nj][r] + bv_[nj];
                const int cm = m0 + wr * 64 + mi * 16 + hi * 4 + r;
                const int cn = n0 + wc * 64 + nj * 16 + lo;
                const int b = cm >> 11, s = cm & (S_ - 1);
                const int h = cn >> 6, d = cn & 63;
                if (wsel == 0)  // fold 0.125 * log2(e) for log2-domain softmax
                    qb[(((size_t)b * H_ + h) * S_ + s) * DH + d] =
                        f2bf(v * 0.18033688011112042f);
                else if (wsel == 1)
                    kb[(((size_t)b * H_ + h) * S_ + s) * DH + d] = f2bf(v);
                else
                    vt[(((size_t)b * H_ + h) * DH + d) * S_ + s] = f2bf(v);
            }
}

// ---------------------------------------------------------------------------
// Final GEMM: out = ctx @ wo^T + bo, 3-pass split-bf16, fp32 output.
// Double-buffered (1 barrier/K-step), 64KB LDS.
// ---------------------------------------------------------------------------
__global__ __launch_bounds__(256) void gemm_out(const u16* __restrict__ Ah,
                                                const u16* __restrict__ Al,
                                                const u16* __restrict__ Wh,
                                                const u16* __restrict__ Wl,
                                                const float* __restrict__ bias,
                                                float* __restrict__ Cout) {
    __shared__ __align__(16) u16 sAh[8192];
    __shared__ __align__(16) u16 sBh[8192];
    __shared__ __align__(16) u16 sAl[8192];
    __shared__ __align__(16) u16 sBl[8192];

    const int tid = threadIdx.x;
    const int l = tid & 63;
    const int w = tid >> 6;
    const int lo = l & 15;
    const int hi = l >> 4;
    const int wr = w >> 1;
    const int wc = w & 1;
    const int L = blockIdx.x;
    const int c = L & 7;
    const int t = L >> 3;
    const int by = c * 8 + (t >> 3);
    const int bx = t & 7;
    const int m0 = by * 128;
    const int n0 = bx * 128;

    auto stage = [&](int k0, int half) {
#pragma unroll
        for (int i = 0; i < 2; ++i) {
            const int p = 256 * i + tid;
            const int row = p >> 2;
            const int ps = p & 3;
            const int sl = ps ^ ((row + (row >> 2)) & 3);
            const int lb = half * 4096 + (256 * i + 64 * w) * 8;
            const size_t ga = (size_t)(m0 + row) * D_ + k0 + 8 * sl;
            const size_t gb = (size_t)(n0 + row) * D_ + k0 + 8 * sl;
            gl16(Ah + ga, &sAh[lb]);
            gl16(Al + ga, &sAl[lb]);
            gl16(Wh + gb, &sBh[lb]);
            gl16(Wl + gb, &sBl[lb]);
        }
    };

    const f32x4 z4 = {0.f, 0.f, 0.f, 0.f};
    f32x4 acc[4][4];
#pragma unroll
    for (int i = 0; i < 4; ++i)
#pragma unroll
        for (int j = 0; j < 4; ++j) acc[i][j] = z4;

    stage(0, 0);
    for (int k0 = 0; k0 < D_; k0 += 32) {
        const int cur = (k0 >> 5) & 1;
        __syncthreads();  // drains prefetched loads; closes prev reads
        if (k0 + 32 < D_) stage(k0 + 32, cur ^ 1);
        const int bufo = cur * 4096;

        bf16x8 ah[4], al_[4], bh[4], bl_[4];
#pragma unroll
        for (int mi = 0; mi < 4; ++mi) {
            const int r = wr * 64 + mi * 16 + lo;
            const int sl = hi ^ ((r + (r >> 2)) & 3);
            ah[mi] = *(const bf16x8*)&sAh[bufo + r * 32 + sl * 8];
            al_[mi] = *(const bf16x8*)&sAl[bufo + r * 32 + sl * 8];
        }
#pragma unroll
        for (int nj = 0; nj < 4; ++nj) {
            const int r = wc * 64 + nj * 16 + lo;
            const int sl = hi ^ ((r + (r >> 2)) & 3);
            bh[nj] = *(const bf16x8*)&sBh[bufo + r * 32 + sl * 8];
            bl_[nj] = *(const bf16x8*)&sBl[bufo + r * 32 + sl * 8];
        }
#pragma unroll
        for (int mi = 0; mi < 4; ++mi)
#pragma unroll
            for (int nj = 0; nj < 4; ++nj) {
                acc[mi][nj] = __builtin_amdgcn_mfma_f32_16x16x32_bf16(
                    ah[mi], bh[nj], acc[mi][nj], 0, 0, 0);
                acc[mi][nj] = __builtin_amdgcn_mfma_f32_16x16x32_bf16(
                    ah[mi], bl_[nj], acc[mi][nj], 0, 0, 0);
                acc[mi][nj] = __builtin_amdgcn_mfma_f32_16x16x32_bf16(
                    al_[mi], bh[nj], acc[mi][nj], 0, 0, 0);
            }
    }

    float bv_[4];
#pragma unroll
    for (int nj = 0; nj < 4; ++nj) bv_[nj] = bias[n0 + wc * 64 + nj * 16 + lo];

#pragma unroll
    for (int mi = 0; mi < 4; ++mi)
#pragma unroll
        for (int nj = 0; nj < 4; ++nj)
#pragma unroll
            for (int r = 0; r < 4; ++r) {
                const int cm = m0 + wr * 64 + mi * 16 + hi * 4 + r;
                const int cn = n0 + wc * 64 + nj * 16 + lo;
                Cout[(size_t)cm * D_ + cn] = acc[mi][nj][r] + bv_[nj];
            }
}

// ---------------------------------------------------------------------------
// MFMA flash attention v8 = attn6 (K,V in LDS; fixed-max softmax; T12
// in-register P transpose) + depth-2 prefetch: 3 rotating K/V buffers,
// raw s_barrier with counted s_waitcnt vmcnt(4) — waits only the OLDER
// in-flight stage (which had a full phase to land), so the per-tile
// barrier no longer drains the just-issued prefetch. Buffer lifetime:
// STAGE(kt+2) writes buf (kt+2)%3 whose readers (phase kt-1) are closed
// by this barrier; RAW: every wave ran vmcnt(4) before the barrier.
// LDS 48KB -> 3 blocks/CU (12 waves).
// ---------------------------------------------------------------------------
__global__ __launch_bounds__(256, 3) void attn8(const u16* __restrict__ Qb,
                                                const u16* __restrict__ Kb,
                                                const u16* __restrict__ Vtg,
                                                u16* __restrict__ chi,
                                                u16* __restrict__ clo) {
    __shared__ __align__(16) u16 KsA[3 * 4096];  // [buf][kv 64][d 64] swizzled
    __shared__ __align__(16) u16 VsA[3 * 4096];  // [buf][d 64][kv 64] swizzled

    const int tid = threadIdx.x;
    const int l = tid & 63;
    const int w = tid >> 6;
    const int lo = l & 15;
    const int hi = l >> 4;
    const int L = blockIdx.x;
    const int c = L & 7;
    const int t = L >> 3;             // 0..127
    const int bh = c * 8 + (t >> 4);  // 0..63
    const int s0 = (t & 15) * 128;
    const size_t base = (size_t)bh * S_ * DH;

    const int sp0 = tid;
    const int srow0 = sp0 >> 3, ssl0 = (sp0 & 7) ^ (srow0 & 7);
    const int sp1 = 256 + tid;
    const int srow1 = sp1 >> 3, ssl1 = (sp1 & 7) ^ (srow1 & 7);
    const int lb0 = (64 * w) * 8;
    const int lb1 = (256 + 64 * w) * 8;

    // Q fragments, 2 q-halves (pre-scaled by 0.125*log2e in the QKV epilogue)
    bf16x8 qa[2][2];
#pragma unroll
    for (int qh = 0; qh < 2; ++qh) {
        const u16* qp = Qb + base + (size_t)(s0 + w * 32 + qh * 16 + lo) * DH;
        qa[qh][0] = *(const bf16x8*)(qp + hi * 8);
        qa[qh][1] = *(const bf16x8*)(qp + hi * 8 + 32);
    }

    const f32x4 zero4 = {0.f, 0.f, 0.f, 0.f};
    f32x4 acc[2][4];
    f32x4 acc_l[2] = {zero4, zero4};
#pragma unroll
    for (int qh = 0; qh < 2; ++qh)
#pragma unroll
        for (int g = 0; g < 4; ++g) acc[qh][g] = zero4;

    const short onebf = (short)0x3F80;  // bf16 1.0
    const bf16x8 ones = {onebf, onebf, onebf, onebf, onebf, onebf, onebf, onebf};

#define STAGE(KT, BUF)                                                         \
    do {                                                                       \
        const size_t kbase = base + (size_t)(KT) * 64 * DH;                    \
        const size_t vbase = base + (size_t)(KT) * 64;                         \
        gl16(Kb + kbase + (size_t)srow0 * DH + 8 * ssl0, &KsA[(BUF)*4096 + lb0]); \
        gl16(Vtg + vbase + (size_t)srow0 * S_ + 8 * ssl0, &VsA[(BUF)*4096 + lb0]); \
        gl16(Kb + kbase + (size_t)srow1 * DH + 8 * ssl1, &KsA[(BUF)*4096 + lb1]); \
        gl16(Vtg + vbase + (size_t)srow1 * S_ + 8 * ssl1, &VsA[(BUF)*4096 + lb1]); \
    } while (0)

    STAGE(0, 0);
    STAGE(1, 1);

    for (int kt = 0; kt < S_ / 64; ++kt) {
        // counted wait: leave STAGE(kt+1)'s 4 loads in flight; drain STAGE(kt)
        if (kt + 1 < S_ / 64)
            asm volatile("s_waitcnt vmcnt(4)" ::: "memory");
        else
            asm volatile("s_waitcnt vmcnt(0)" ::: "memory");
        __builtin_amdgcn_s_barrier();
        if (kt + 2 < S_ / 64) STAGE(kt + 2, (kt + 2) % 3);

        const int cur = kt % 3;
        const u16* Ks = &KsA[cur * 4096];
        const u16* Vs = &VsA[cur * 4096];

        // --- QK^T (swapped), K-frag shared across both q-halves
        f32x4 sc[2][4];
#pragma unroll
        for (int qh = 0; qh < 2; ++qh)
#pragma unroll
            for (int f = 0; f < 4; ++f) sc[qh][f] = zero4;
        __builtin_amdgcn_s_setprio(1);
#pragma unroll
        for (int f = 0; f < 4; ++f) {
            const int kr = lo + 16 * f;
            const int ksw = (kr & 7) << 3;
#pragma unroll
            for (int ks = 0; ks < 2; ++ks) {
                bf16x8 kf = *(const bf16x8*)&Ks[kr * 64 + ((hi * 8 + 32 * ks) ^ ksw)];
                sc[0][f] = __builtin_amdgcn_mfma_f32_16x16x32_bf16(kf, qa[0][ks], sc[0][f], 0, 0, 0);
                sc[1][f] = __builtin_amdgcn_mfma_f32_16x16x32_bf16(kf, qa[1][ks], sc[1][f], 0, 0, 0);
            }
        }
        __builtin_amdgcn_s_setprio(0);

        // --- p = exp2(sc); pack + permlane into PV A-fragments (no LDS)
        bf16x8 pa[2][2];
#pragma unroll
        for (int qh = 0; qh < 2; ++qh) {
            u32 T[2][4];
#pragma unroll
            for (int ks = 0; ks < 2; ++ks)
#pragma unroll
                for (int cc = 0; cc < 2; ++cc) {
                    u32 X = cvtpk(fexp2(sc[qh][2 * ks][2 * cc]),
                                  fexp2(sc[qh][2 * ks][2 * cc + 1]));
                    u32 Y = cvtpk(fexp2(sc[qh][2 * ks + 1][2 * cc]),
                                  fexp2(sc[qh][2 * ks + 1][2 * cc + 1]));
                    pswap32(X, Y);
                    pswap16(X, Y);
                    T[ks][cc] = X;
                    T[ks][2 + cc] = Y;
                }
#pragma unroll
            for (int ks = 0; ks < 2; ++ks) {
                u32x4 word = {T[ks][0], T[ks][1], T[ks][2], T[ks][3]};
                pa[qh][ks] = __builtin_bit_cast(bf16x8, word);
            }
        }

        // --- PV (swapped) + MFMA row-sum; V-frag shared across q-halves
        __builtin_amdgcn_s_setprio(1);
        acc_l[0] = __builtin_amdgcn_mfma_f32_16x16x32_bf16(ones, pa[0][0], acc_l[0], 0, 0, 0);
        acc_l[0] = __builtin_amdgcn_mfma_f32_16x16x32_bf16(ones, pa[0][1], acc_l[0], 0, 0, 0);
        acc_l[1] = __builtin_amdgcn_mfma_f32_16x16x32_bf16(ones, pa[1][0], acc_l[1], 0, 0, 0);
        acc_l[1] = __builtin_amdgcn_mfma_f32_16x16x32_bf16(ones, pa[1][1], acc_l[1], 0, 0, 0);
#pragma unroll
        for (int g = 0; g < 4; ++g) {
            const int vr = lo + 16 * g;
            const int vsw = (vr & 7) << 3;
#pragma unroll
            for (int ks = 0; ks < 2; ++ks) {
                bf16x8 vf = *(const bf16x8*)&Vs[vr * 64 + ((hi * 8 + 32 * ks) ^ vsw)];
                acc[0][g] = __builtin_amdgcn_mfma_f32_16x16x32_bf16(vf, pa[0][ks], acc[0][g], 0, 0, 0);
                acc[1][g] = __builtin_amdgcn_mfma_f32_16x16x32_bf16(vf, pa[1][ks], acc[1][g], 0, 0, 0);
            }
        }
        __builtin_amdgcn_s_setprio(0);
    }
#undef STAGE

    // epilogue: O[q][d] / l, split hi/lo bf16, u16x4 stores
    const int b = bh >> 4;
    const int h = bh & 15;
#pragma unroll
    for (int qh = 0; qh < 2; ++qh) {
        const float inv = 1.f / acc_l[qh][0];
        const int row = s0 + w * 32 + qh * 16 + lo;
#pragma unroll
        for (int g = 0; g < 4; ++g) {
            u16x4 hh, ll;
#pragma unroll
            for (int r = 0; r < 4; ++r) {
                const float v = acc[qh][g][r] * inv;
                hh[r] = f2bf_hw(v);
                ll[r] = f2bf_hw(v - bf2f(hh[r]));
            }
            const size_t off = ((size_t)b * S_ + row) * D_ + h * 64 + 16 * g + hi * 4;
            *(u16x4*)&chi[off] = hh;
            *(u16x4*)&clo[off] = ll;
        }
    }
}

// ---------------------------------------------------------------------------
extern "C" void kernel_launch(void* const* d_in, const int* in_sizes, int n_in,
                              void* d_out, int out_size, void* d_ws, size_t ws_size,
                              hipStream_t stream) {
    const float* x  = (const float*)d_in[0];
    const float* wq = (const float*)d_in[1];
    const float* bq = (const float*)d_in[2];
    const float* wk = (const float*)d_in[3];
    const float* bk = (const float*)d_in[4];
    const float* wv = (const float*)d_in[5];
    const float* bv = (const float*)d_in[6];
    const float* wo = (const float*)d_in[7];
    const float* bo = (const float*)d_in[8];
    float* out = (float*)d_out;

    const size_t MD = (size_t)M_ * D_;  // 8388608
    const size_t WD = (size_t)D_ * D_;  // 1048576
    u16* ws = (u16*)d_ws;
    u16* xh  = ws;             // MD
    u16* wh  = xh + MD;        // 3*WD (wq,wk,wv bf16)
    u16* woh = wh + 3 * WD;    // WD
    u16* wol = woh + WD;       // WD
    u16* qb  = wol + WD;       // MD
    u16* kb  = qb + MD;        // MD
    u16* vt  = kb + MD;        // MD
    u16* clo = vt + MD;        // MD
    u16* chi = xh;             // alias: x consumed by QKV GEMM before attn writes

    dim3 blk(256);
    // float4 work items: x 2M + 3 W casts 768K + wo split 256K = 3145728
    prep<<<dim3(12288), blk, 0, stream>>>(x, wq, wk, wv, wo, xh, wh, woh, wol);
    gemm_qkv<<<dim3(768), dim3(512), 0, stream>>>(xh, wh, bq, bk, bv, qb, kb, vt);
    attn8<<<dim3(1024), blk, 0, stream>>>(qb, kb, vt, chi, clo);
    gemm_out<<<dim3(512), blk, 0, stream>>>(chi, clo, woh, wol, bo, out);
}

// Round 14
// 214.885 us; speedup vs baseline: 1.6716x; 1.0428x over previous
//
#include <hip/hip_runtime.h>
#include <hip/hip_bf16.h>

#define B_  4
#define S_  2048
#define D_  1024
#define H_  16
#define DH  64
#define M_  (B_ * S_)   // 8192

typedef unsigned short u16;
typedef unsigned int u32;
typedef __attribute__((ext_vector_type(8))) short bf16x8;
typedef __attribute__((ext_vector_type(4))) float f32x4;
typedef __attribute__((ext_vector_type(4))) unsigned short u16x4;
typedef __attribute__((ext_vector_type(4))) unsigned int u32x4;

static __device__ __forceinline__ u16 f2bf(float x) {
    union { float f; unsigned u; } c;
    c.f = x;
    const unsigned u = c.u;
    return (u16)((u + 0x7FFFu + ((u >> 16) & 1u)) >> 16);
}
static __device__ __forceinline__ float bf2f(u16 h) {
    union { unsigned u; float f; } c;
    c.u = ((unsigned)h) << 16;
    return c.f;
}
#ifdef __BF16_MANT_DIG__
static __device__ __forceinline__ u16 f2bf_hw(float x) {
    __bf16 b = (__bf16)x;
    return __builtin_bit_cast(u16, b);
}
#else
#define f2bf_hw f2bf
#endif
#if __has_builtin(__builtin_amdgcn_exp2f)
#define fexp2 __builtin_amdgcn_exp2f
#else
#define fexp2 exp2f
#endif
// async 16B global->LDS (LDS dest = wave-uniform base + lane*16)
static __device__ __forceinline__ void gl16(const u16* g, u16* l) {
    __builtin_amdgcn_global_load_lds(
        (const __attribute__((address_space(1))) unsigned int*)g,
        (__attribute__((address_space(3))) unsigned int*)l, 16, 0, 0);
}
// v_cvt_pk_bf16_f32: dst.lo16=bf16(a), dst.hi16=bf16(b)
static __device__ __forceinline__ u32 cvtpk(float a, float b) {
    u32 r;
    asm("v_cvt_pk_bf16_f32 %0, %1, %2" : "=v"(r) : "v"(a), "v"(b));
    return r;
}
// swap d[32:63] <-> s[0:31]
static __device__ __forceinline__ void pswap32(u32& d, u32& s) {
    asm volatile("v_permlane32_swap_b32 %0, %1" : "+v"(d), "+v"(s));
}
// swap d[16:31]<->s[0:15], d[48:63]<->s[32:47]
static __device__ __forceinline__ void pswap16(u32& d, u32& s) {
    asm volatile("v_permlane16_swap_b32 %0, %1" : "+v"(d), "+v"(s));
}

// ---------------------------------------------------------------------------
// Fused prep: cast x,wq,wk,wv -> bf16; split wo -> hi/lo bf16. One launch.
// ---------------------------------------------------------------------------
__global__ __launch_bounds__(256) void prep(const float* __restrict__ x,
                                            const float* __restrict__ wq,
                                            const float* __restrict__ wk,
                                            const float* __restrict__ wv,
                                            const float* __restrict__ wo,
                                            u16* __restrict__ xh,
                                            u16* __restrict__ wh,   // 3 blocks
                                            u16* __restrict__ woh,
                                            u16* __restrict__ wol) {
    const size_t NX = (size_t)M_ * D_ / 4;  // 2097152
    const size_t NW = (size_t)D_ * D_ / 4;  // 262144
    const size_t i = (size_t)blockIdx.x * 256 + threadIdx.x;
    if (i < NX) {
        float4 v = ((const float4*)x)[i];
        u16x4 h;
        h[0] = f2bf_hw(v.x); h[1] = f2bf_hw(v.y);
        h[2] = f2bf_hw(v.z); h[3] = f2bf_hw(v.w);
        ((u16x4*)xh)[i] = h;
    } else if (i < NX + 3 * NW) {
        const size_t j = i - NX;
        const int sel = (int)(j / NW);
        const size_t k = j - (size_t)sel * NW;
        const float* src = sel == 0 ? wq : sel == 1 ? wk : wv;
        float4 v = ((const float4*)src)[k];
        u16x4 h;
        h[0] = f2bf_hw(v.x); h[1] = f2bf_hw(v.y);
        h[2] = f2bf_hw(v.z); h[3] = f2bf_hw(v.w);
        ((u16x4*)(wh + (size_t)sel * D_ * D_))[k] = h;
    } else {
        const size_t k = i - NX - 3 * NW;
        float4 v = ((const float4*)wo)[k];
        u16x4 h, l;
        float vv[4] = {v.x, v.y, v.z, v.w};
#pragma unroll
        for (int j = 0; j < 4; ++j) {
            h[j] = f2bf_hw(vv[j]);
            l[j] = f2bf_hw(vv[j] - bf2f(h[j]));
        }
        ((u16x4*)woh)[k] = h;
        ((u16x4*)wol)[k] = l;
    }
}

// ---------------------------------------------------------------------------
// Merged QKV GEMM: {Q,K,V} = x @ W{q,k,v}^T + b, 1-pass bf16, double-buffered
// (1 barrier/K-step). 256x128 tile, 8 waves (512 thr, 4x2 quadrants).
// Grid 768, XCD-chunked, W-tile-major within XCD (A-slice 2MB L2-resident).
// ---------------------------------------------------------------------------
__global__ __launch_bounds__(512) void gemm_qkv(const u16* __restrict__ xh,
                                                const u16* __restrict__ whb,
                                                const float* __restrict__ bq,
                                                const float* __restrict__ bk,
                                                const float* __restrict__ bv,
                                                u16* __restrict__ qb,
                                                u16* __restrict__ kb,
                                                u16* __restrict__ vt) {
    __shared__ __align__(16) u16 sA[2 * 8192];  // [buf][256 rows][32 cols]
    __shared__ __align__(16) u16 sB[2 * 4096];  // [buf][128 rows][32 cols]

    const int tid = threadIdx.x;
    const int l = tid & 63;
    const int w = tid >> 6;      // 0..7
    const int lo = l & 15;
    const int hi = l >> 4;
    const int wr = w >> 1;       // 0..3 quadrant row
    const int wc = w & 1;        // 0..1 quadrant col
    const int L = blockIdx.x;
    const int c = L & 7;
    const int t = L >> 3;            // 0..95
    const int by = c * 4 + (t & 3);  // 0..31
    const int bxs = t >> 2;          // 0..23
    const int wsel = bxs >> 3;       // 0..2
    const int bx = bxs & 7;          // 0..7
    const int m0 = by * 256;
    const int n0 = bx * 128;

    const u16* W = whb + (size_t)wsel * D_ * D_;
    const float* bias = wsel == 0 ? bq : wsel == 1 ? bk : bv;

    auto stage = [&](int k0, int buf) {
#pragma unroll
        for (int i = 0; i < 2; ++i) {       // A: 1024 slots / 512 thr
            const int p = 512 * i + tid;
            const int row = p >> 2;          // 0..255
            const int ps = p & 3;
            const int sl = ps ^ ((row + (row >> 2)) & 3);
            const int lb = buf * 8192 + (512 * i + 64 * w) * 8;
            gl16(xh + (size_t)(m0 + row) * D_ + k0 + 8 * sl, &sA[lb]);
        }
        {                                    // B: 512 slots / 512 thr
            const int p = tid;
            const int row = p >> 2;          // 0..127
            const int ps = p & 3;
            const int sl = ps ^ ((row + (row >> 2)) & 3);
            const int lb = buf * 4096 + (64 * w) * 8;
            gl16(W + (size_t)(n0 + row) * D_ + k0 + 8 * sl, &sB[lb]);
        }
    };

    const f32x4 z4 = {0.f, 0.f, 0.f, 0.f};
    f32x4 acc[4][4];
#pragma unroll
    for (int i = 0; i < 4; ++i)
#pragma unroll
        for (int j = 0; j < 4; ++j) acc[i][j] = z4;

    stage(0, 0);
    for (int k0 = 0; k0 < D_; k0 += 32) {
        const int cur = (k0 >> 5) & 1;
        __syncthreads();  // drains prefetched loads; closes prev reads
        if (k0 + 32 < D_) stage(k0 + 32, cur ^ 1);

        bf16x8 ah[4], bh[4];
#pragma unroll
        for (int mi = 0; mi < 4; ++mi) {
            const int r = wr * 64 + mi * 16 + lo;
            const int sl = hi ^ ((r + (r >> 2)) & 3);
            ah[mi] = *(const bf16x8*)&sA[cur * 8192 + r * 32 + sl * 8];
        }
#pragma unroll
        for (int nj = 0; nj < 4; ++nj) {
            const int r = wc * 64 + nj * 16 + lo;
            const int sl = hi ^ ((r + (r >> 2)) & 3);
            bh[nj] = *(const bf16x8*)&sB[cur * 4096 + r * 32 + sl * 8];
        }
#pragma unroll
        for (int mi = 0; mi < 4; ++mi)
#pragma unroll
            for (int nj = 0; nj < 4; ++nj)
                acc[mi][nj] = __builtin_amdgcn_mfma_f32_16x16x32_bf16(
                    ah[mi], bh[nj], acc[mi][nj], 0, 0, 0);
    }

    float bv_[4];
#pragma unroll
    for (int nj = 0; nj < 4; ++nj) bv_[nj] = bias[n0 + wc * 64 + nj * 16 + lo];

#pragma unroll
    for (int mi = 0; mi < 4; ++mi)
#pragma unroll
        for (int nj = 0; nj < 4; ++nj)
#pragma unroll
            for (int r = 0; r < 4; ++r) {
                const float v = acc[mi][nj][r] + bv_[nj];
                const int cm = m0 + wr * 64 + mi * 16 + hi * 4 + r;
                const int cn = n0 + wc * 64 + nj * 16 + lo;
                const int b = cm >> 11, s = cm & (S_ - 1);
                const int h = cn >> 6, d = cn & 63;
                if (wsel == 0)  // fold 0.125 * log2(e) for log2-domain softmax
                    qb[(((size_t)b * H_ + h) * S_ + s) * DH + d] =
                        f2bf(v * 0.18033688011112042f);
                else if (wsel == 1)
                    kb[(((size_t)b * H_ + h) * S_ + s) * DH + d] = f2bf(v);
                else
                    vt[(((size_t)b * H_ + h) * DH + d) * S_ + s] = f2bf(v);
            }
}

// ---------------------------------------------------------------------------
// Final GEMM: out = ctx @ wo^T + bo, 3-pass split-bf16, fp32 output.
// Double-buffered (1 barrier/K-step), 64KB LDS.
// ---------------------------------------------------------------------------
__global__ __launch_bounds__(256) void gemm_out(const u16* __restrict__ Ah,
                                                const u16* __restrict__ Al,
                                                const u16* __restrict__ Wh,
                                                const u16* __restrict__ Wl,
                                                const float* __restrict__ bias,
                                                float* __restrict__ Cout) {
    __shared__ __align__(16) u16 sAh[8192];
    __shared__ __align__(16) u16 sBh[8192];
    __shared__ __align__(16) u16 sAl[8192];
    __shared__ __align__(16) u16 sBl[8192];

    const int tid = threadIdx.x;
    const int l = tid & 63;
    const int w = tid >> 6;
    const int lo = l & 15;
    const int hi = l >> 4;
    const int wr = w >> 1;
    const int wc = w & 1;
    const int L = blockIdx.x;
    const int c = L & 7;
    const int t = L >> 3;
    const int by = c * 8 + (t >> 3);
    const int bx = t & 7;
    const int m0 = by * 128;
    const int n0 = bx * 128;

    auto stage = [&](int k0, int half) {
#pragma unroll
        for (int i = 0; i < 2; ++i) {
            const int p = 256 * i + tid;
            const int row = p >> 2;
            const int ps = p & 3;
            const int sl = ps ^ ((row + (row >> 2)) & 3);
            const int lb = half * 4096 + (256 * i + 64 * w) * 8;
            const size_t ga = (size_t)(m0 + row) * D_ + k0 + 8 * sl;
            const size_t gb = (size_t)(n0 + row) * D_ + k0 + 8 * sl;
            gl16(Ah + ga, &sAh[lb]);
            gl16(Al + ga, &sAl[lb]);
            gl16(Wh + gb, &sBh[lb]);
            gl16(Wl + gb, &sBl[lb]);
        }
    };

    const f32x4 z4 = {0.f, 0.f, 0.f, 0.f};
    f32x4 acc[4][4];
#pragma unroll
    for (int i = 0; i < 4; ++i)
#pragma unroll
        for (int j = 0; j < 4; ++j) acc[i][j] = z4;

    stage(0, 0);
    for (int k0 = 0; k0 < D_; k0 += 32) {
        const int cur = (k0 >> 5) & 1;
        __syncthreads();  // drains prefetched loads; closes prev reads
        if (k0 + 32 < D_) stage(k0 + 32, cur ^ 1);
        const int bufo = cur * 4096;

        bf16x8 ah[4], al_[4], bh[4], bl_[4];
#pragma unroll
        for (int mi = 0; mi < 4; ++mi) {
            const int r = wr * 64 + mi * 16 + lo;
            const int sl = hi ^ ((r + (r >> 2)) & 3);
            ah[mi] = *(const bf16x8*)&sAh[bufo + r * 32 + sl * 8];
            al_[mi] = *(const bf16x8*)&sAl[bufo + r * 32 + sl * 8];
        }
#pragma unroll
        for (int nj = 0; nj < 4; ++nj) {
            const int r = wc * 64 + nj * 16 + lo;
            const int sl = hi ^ ((r + (r >> 2)) & 3);
            bh[nj] = *(const bf16x8*)&sBh[bufo + r * 32 + sl * 8];
            bl_[nj] = *(const bf16x8*)&sBl[bufo + r * 32 + sl * 8];
        }
#pragma unroll
        for (int mi = 0; mi < 4; ++mi)
#pragma unroll
            for (int nj = 0; nj < 4; ++nj) {
                acc[mi][nj] = __builtin_amdgcn_mfma_f32_16x16x32_bf16(
                    ah[mi], bh[nj], acc[mi][nj], 0, 0, 0);
                acc[mi][nj] = __builtin_amdgcn_mfma_f32_16x16x32_bf16(
                    ah[mi], bl_[nj], acc[mi][nj], 0, 0, 0);
                acc[mi][nj] = __builtin_amdgcn_mfma_f32_16x16x32_bf16(
                    al_[mi], bh[nj], acc[mi][nj], 0, 0, 0);
            }
    }

    float bv_[4];
#pragma unroll
    for (int nj = 0; nj < 4; ++nj) bv_[nj] = bias[n0 + wc * 64 + nj * 16 + lo];

#pragma unroll
    for (int mi = 0; mi < 4; ++mi)
#pragma unroll
        for (int nj = 0; nj < 4; ++nj)
#pragma unroll
            for (int r = 0; r < 4; ++r) {
                const int cm = m0 + wr * 64 + mi * 16 + hi * 4 + r;
                const int cn = n0 + wc * 64 + nj * 16 + lo;
                Cout[(size_t)cm * D_ + cn] = acc[mi][nj][r] + bv_[nj];
            }
}

// ---------------------------------------------------------------------------
// MFMA flash attention, fixed-max softmax, in-register P via cvt_pk+permlane
// (T12). Round-8/10 proven version (setprio present). LDS 32KB, 4 blocks/CU.
// ---------------------------------------------------------------------------
__global__ __launch_bounds__(256, 4) void attn6(const u16* __restrict__ Qb,
                                                const u16* __restrict__ Kb,
                                                const u16* __restrict__ Vtg,
                                                u16* __restrict__ chi,
                                                u16* __restrict__ clo) {
    __shared__ __align__(16) u16 KsA[2 * 4096];  // [buf][kv 64][d 64] swizzled
    __shared__ __align__(16) u16 VsA[2 * 4096];  // [buf][d 64][kv 64] swizzled

    const int tid = threadIdx.x;
    const int l = tid & 63;
    const int w = tid >> 6;
    const int lo = l & 15;
    const int hi = l >> 4;
    const int L = blockIdx.x;
    const int c = L & 7;
    const int t = L >> 3;             // 0..127
    const int bh = c * 8 + (t >> 4);  // 0..63
    const int s0 = (t & 15) * 128;
    const size_t base = (size_t)bh * S_ * DH;

    const int sp0 = tid;
    const int srow0 = sp0 >> 3, ssl0 = (sp0 & 7) ^ (srow0 & 7);
    const int sp1 = 256 + tid;
    const int srow1 = sp1 >> 3, ssl1 = (sp1 & 7) ^ (srow1 & 7);
    const int lb0 = (64 * w) * 8;
    const int lb1 = (256 + 64 * w) * 8;

    // Q fragments, 2 q-halves (pre-scaled by 0.125*log2e in the QKV epilogue)
    bf16x8 qa[2][2];
#pragma unroll
    for (int qh = 0; qh < 2; ++qh) {
        const u16* qp = Qb + base + (size_t)(s0 + w * 32 + qh * 16 + lo) * DH;
        qa[qh][0] = *(const bf16x8*)(qp + hi * 8);
        qa[qh][1] = *(const bf16x8*)(qp + hi * 8 + 32);
    }

    const f32x4 zero4 = {0.f, 0.f, 0.f, 0.f};
    f32x4 acc[2][4];
    f32x4 acc_l[2] = {zero4, zero4};
#pragma unroll
    for (int qh = 0; qh < 2; ++qh)
#pragma unroll
        for (int g = 0; g < 4; ++g) acc[qh][g] = zero4;

    const short onebf = (short)0x3F80;  // bf16 1.0
    const bf16x8 ones = {onebf, onebf, onebf, onebf, onebf, onebf, onebf, onebf};

#define STAGE(KT, HALF)                                                        \
    do {                                                                       \
        const size_t kbase = base + (size_t)(KT) * 64 * DH;                    \
        const size_t vbase = base + (size_t)(KT) * 64;                         \
        gl16(Kb + kbase + (size_t)srow0 * DH + 8 * ssl0, &KsA[(HALF)*4096 + lb0]); \
        gl16(Vtg + vbase + (size_t)srow0 * S_ + 8 * ssl0, &VsA[(HALF)*4096 + lb0]); \
        gl16(Kb + kbase + (size_t)srow1 * DH + 8 * ssl1, &KsA[(HALF)*4096 + lb1]); \
        gl16(Vtg + vbase + (size_t)srow1 * S_ + 8 * ssl1, &VsA[(HALF)*4096 + lb1]); \
    } while (0)

    STAGE(0, 0);

    for (int kt = 0; kt < S_ / 64; ++kt) {
        const int cur = kt & 1;
        __syncthreads();  // drains vmcnt -> tile kt staged; closes prev reads
        if (kt + 1 < S_ / 64) STAGE(kt + 1, cur ^ 1);
        const u16* Ks = &KsA[cur * 4096];
        const u16* Vs = &VsA[cur * 4096];

        // --- QK^T (swapped), K-frag shared across both q-halves
        f32x4 sc[2][4];
#pragma unroll
        for (int qh = 0; qh < 2; ++qh)
#pragma unroll
            for (int f = 0; f < 4; ++f) sc[qh][f] = zero4;
        __builtin_amdgcn_s_setprio(1);
#pragma unroll
        for (int f = 0; f < 4; ++f) {
            const int kr = lo + 16 * f;
            const int ksw = (kr & 7) << 3;
#pragma unroll
            for (int ks = 0; ks < 2; ++ks) {
                bf16x8 kf = *(const bf16x8*)&Ks[kr * 64 + ((hi * 8 + 32 * ks) ^ ksw)];
                sc[0][f] = __builtin_amdgcn_mfma_f32_16x16x32_bf16(kf, qa[0][ks], sc[0][f], 0, 0, 0);
                sc[1][f] = __builtin_amdgcn_mfma_f32_16x16x32_bf16(kf, qa[1][ks], sc[1][f], 0, 0, 0);
            }
        }
        __builtin_amdgcn_s_setprio(0);

        // --- p = exp2(sc); pack + permlane into PV A-fragments (no LDS)
        bf16x8 pa[2][2];
#pragma unroll
        for (int qh = 0; qh < 2; ++qh) {
            u32 T[2][4];
#pragma unroll
            for (int ks = 0; ks < 2; ++ks)
#pragma unroll
                for (int cc = 0; cc < 2; ++cc) {
                    u32 X = cvtpk(fexp2(sc[qh][2 * ks][2 * cc]),
                                  fexp2(sc[qh][2 * ks][2 * cc + 1]));
                    u32 Y = cvtpk(fexp2(sc[qh][2 * ks + 1][2 * cc]),
                                  fexp2(sc[qh][2 * ks + 1][2 * cc + 1]));
                    pswap32(X, Y);
                    pswap16(X, Y);
                    T[ks][cc] = X;
                    T[ks][2 + cc] = Y;
                }
#pragma unroll
            for (int ks = 0; ks < 2; ++ks) {
                u32x4 word = {T[ks][0], T[ks][1], T[ks][2], T[ks][3]};
                pa[qh][ks] = __builtin_bit_cast(bf16x8, word);
            }
        }

        // --- PV (swapped) + MFMA row-sum; V-frag shared across q-halves
        __builtin_amdgcn_s_setprio(1);
        acc_l[0] = __builtin_amdgcn_mfma_f32_16x16x32_bf16(ones, pa[0][0], acc_l[0], 0, 0, 0);
        acc_l[0] = __builtin_amdgcn_mfma_f32_16x16x32_bf16(ones, pa[0][1], acc_l[0], 0, 0, 0);
        acc_l[1] = __builtin_amdgcn_mfma_f32_16x16x32_bf16(ones, pa[1][0], acc_l[1], 0, 0, 0);
        acc_l[1] = __builtin_amdgcn_mfma_f32_16x16x32_bf16(ones, pa[1][1], acc_l[1], 0, 0, 0);
#pragma unroll
        for (int g = 0; g < 4; ++g) {
            const int vr = lo + 16 * g;
            const int vsw = (vr & 7) << 3;
#pragma unroll
            for (int ks = 0; ks < 2; ++ks) {
                bf16x8 vf = *(const bf16x8*)&Vs[vr * 64 + ((hi * 8 + 32 * ks) ^ vsw)];
                acc[0][g] = __builtin_amdgcn_mfma_f32_16x16x32_bf16(vf, pa[0][ks], acc[0][g], 0, 0, 0);
                acc[1][g] = __builtin_amdgcn_mfma_f32_16x16x32_bf16(vf, pa[1][ks], acc[1][g], 0, 0, 0);
            }
        }
        __builtin_amdgcn_s_setprio(0);
    }
#undef STAGE

    // epilogue: O[q][d] / l, split hi/lo bf16, u16x4 stores
    const int b = bh >> 4;
    const int h = bh & 15;
#pragma unroll
    for (int qh = 0; qh < 2; ++qh) {
        const float inv = 1.f / acc_l[qh][0];
        const int row = s0 + w * 32 + qh * 16 + lo;
#pragma unroll
        for (int g = 0; g < 4; ++g) {
            u16x4 hh, ll;
#pragma unroll
            for (int r = 0; r < 4; ++r) {
                const float v = acc[qh][g][r] * inv;
                hh[r] = f2bf_hw(v);
                ll[r] = f2bf_hw(v - bf2f(hh[r]));
            }
            const size_t off = ((size_t)b * S_ + row) * D_ + h * 64 + 16 * g + hi * 4;
            *(u16x4*)&chi[off] = hh;
            *(u16x4*)&clo[off] = ll;
        }
    }
}

// ---------------------------------------------------------------------------
extern "C" void kernel_launch(void* const* d_in, const int* in_sizes, int n_in,
                              void* d_out, int out_size, void* d_ws, size_t ws_size,
                              hipStream_t stream) {
    const float* x  = (const float*)d_in[0];
    const float* wq = (const float*)d_in[1];
    const float* bq = (const float*)d_in[2];
    const float* wk = (const float*)d_in[3];
    const float* bk = (const float*)d_in[4];
    const float* wv = (const float*)d_in[5];
    const float* bv = (const float*)d_in[6];
    const float* wo = (const float*)d_in[7];
    const float* bo = (const float*)d_in[8];
    float* out = (float*)d_out;

    const size_t MD = (size_t)M_ * D_;  // 8388608
    const size_t WD = (size_t)D_ * D_;  // 1048576
    u16* ws = (u16*)d_ws;
    u16* xh  = ws;             // MD
    u16* wh  = xh + MD;        // 3*WD (wq,wk,wv bf16)
    u16* woh = wh + 3 * WD;    // WD
    u16* wol = woh + WD;       // WD
    u16* qb  = wol + WD;       // MD
    u16* kb  = qb + MD;        // MD
    u16* vt  = kb + MD;        // MD
    u16* clo = vt + MD;        // MD
    u16* chi = xh;             // alias: x consumed by QKV GEMM before attn writes

    dim3 blk(256);
    // float4 work items: x 2M + 3 W casts 768K + wo split 256K = 3145728
    prep<<<dim3(12288), blk, 0, stream>>>(x, wq, wk, wv, wo, xh, wh, woh, wol);
    gemm_qkv<<<dim3(768), dim3(512), 0, stream>>>(xh, wh, bq, bk, bv, qb, kb, vt);
    attn6<<<dim3(1024), blk, 0, stream>>>(qb, kb, vt, chi, clo);
    gemm_out<<<dim3(512), blk, 0, stream>>>(chi, clo, woh, wol, bo, out);
}

// Round 15
// 187.457 us; speedup vs baseline: 1.9162x; 1.1463x over previous
//
#include <hip/hip_runtime.h>
#include <hip/hip_bf16.h>

#define B_  4
#define S_  2048
#define D_  1024
#define H_  16
#define DH  64
#define M_  (B_ * S_)   // 8192

typedef unsigned short u16;
typedef unsigned int u32;
typedef __attribute__((ext_vector_type(8))) short bf16x8;
typedef __attribute__((ext_vector_type(4))) float f32x4;
typedef __attribute__((ext_vector_type(4))) unsigned short u16x4;
typedef __attribute__((ext_vector_type(4))) unsigned int u32x4;

static __device__ __forceinline__ u16 f2bf(float x) {
    union { float f; unsigned u; } c;
    c.f = x;
    const unsigned u = c.u;
    return (u16)((u + 0x7FFFu + ((u >> 16) & 1u)) >> 16);
}
static __device__ __forceinline__ float bf2f(u16 h) {
    union { unsigned u; float f; } c;
    c.u = ((unsigned)h) << 16;
    return c.f;
}
#ifdef __BF16_MANT_DIG__
static __device__ __forceinline__ u16 f2bf_hw(float x) {
    __bf16 b = (__bf16)x;
    return __builtin_bit_cast(u16, b);
}
#else
#define f2bf_hw f2bf
#endif
#if __has_builtin(__builtin_amdgcn_exp2f)
#define fexp2 __builtin_amdgcn_exp2f
#else
#define fexp2 exp2f
#endif
// async 16B global->LDS (LDS dest = wave-uniform base + lane*16)
static __device__ __forceinline__ void gl16(const u16* g, u16* l) {
    __builtin_amdgcn_global_load_lds(
        (const __attribute__((address_space(1))) unsigned int*)g,
        (__attribute__((address_space(3))) unsigned int*)l, 16, 0, 0);
}
// v_cvt_pk_bf16_f32: dst.lo16=bf16(a), dst.hi16=bf16(b)
static __device__ __forceinline__ u32 cvtpk(float a, float b) {
    u32 r;
    asm("v_cvt_pk_bf16_f32 %0, %1, %2" : "=v"(r) : "v"(a), "v"(b));
    return r;
}
// swap d[32:63] <-> s[0:31]
static __device__ __forceinline__ void pswap32(u32& d, u32& s) {
    asm volatile("v_permlane32_swap_b32 %0, %1" : "+v"(d), "+v"(s));
}
// swap d[16:31]<->s[0:15], d[48:63]<->s[32:47]
static __device__ __forceinline__ void pswap16(u32& d, u32& s) {
    asm volatile("v_permlane16_swap_b32 %0, %1" : "+v"(d), "+v"(s));
}

// ---------------------------------------------------------------------------
// Fused prep: cast x,wq,wk,wv,wo -> bf16. One launch.
// (wo no longer needs a hi/lo split: the output GEMM is 1-pass bf16 now.)
// ---------------------------------------------------------------------------
__global__ __launch_bounds__(256) void prep(const float* __restrict__ x,
                                            const float* __restrict__ wq,
                                            const float* __restrict__ wk,
                                            const float* __restrict__ wv,
                                            const float* __restrict__ wo,
                                            u16* __restrict__ xh,
                                            u16* __restrict__ wh,   // 3 blocks
                                            u16* __restrict__ woh) {
    const size_t NX = (size_t)M_ * D_ / 4;  // 2097152
    const size_t NW = (size_t)D_ * D_ / 4;  // 262144
    const size_t i = (size_t)blockIdx.x * 256 + threadIdx.x;
    if (i < NX) {
        float4 v = ((const float4*)x)[i];
        u16x4 h;
        h[0] = f2bf_hw(v.x); h[1] = f2bf_hw(v.y);
        h[2] = f2bf_hw(v.z); h[3] = f2bf_hw(v.w);
        ((u16x4*)xh)[i] = h;
    } else if (i < NX + 3 * NW) {
        const size_t j = i - NX;
        const int sel = (int)(j / NW);
        const size_t k = j - (size_t)sel * NW;
        const float* src = sel == 0 ? wq : sel == 1 ? wk : wv;
        float4 v = ((const float4*)src)[k];
        u16x4 h;
        h[0] = f2bf_hw(v.x); h[1] = f2bf_hw(v.y);
        h[2] = f2bf_hw(v.z); h[3] = f2bf_hw(v.w);
        ((u16x4*)(wh + (size_t)sel * D_ * D_))[k] = h;
    } else {
        const size_t k = i - NX - 3 * NW;
        float4 v = ((const float4*)wo)[k];
        u16x4 h;
        h[0] = f2bf_hw(v.x); h[1] = f2bf_hw(v.y);
        h[2] = f2bf_hw(v.z); h[3] = f2bf_hw(v.w);
        ((u16x4*)woh)[k] = h;
    }
}

// ---------------------------------------------------------------------------
// Merged QKV GEMM: {Q,K,V} = x @ W{q,k,v}^T + b, 1-pass bf16, double-buffered
// (1 barrier/K-step). 256x128 tile, 8 waves (512 thr, 4x2 quadrants).
// Grid 768, XCD-chunked, W-tile-major within XCD (A-slice 2MB L2-resident).
// UNCHANGED from round 14.
// ---------------------------------------------------------------------------
__global__ __launch_bounds__(512) void gemm_qkv(const u16* __restrict__ xh,
                                                const u16* __restrict__ whb,
                                                const float* __restrict__ bq,
                                                const float* __restrict__ bk,
                                                const float* __restrict__ bv,
                                                u16* __restrict__ qb,
                                                u16* __restrict__ kb,
                                                u16* __restrict__ vt) {
    __shared__ __align__(16) u16 sA[2 * 8192];  // [buf][256 rows][32 cols]
    __shared__ __align__(16) u16 sB[2 * 4096];  // [buf][128 rows][32 cols]

    const int tid = threadIdx.x;
    const int l = tid & 63;
    const int w = tid >> 6;      // 0..7
    const int lo = l & 15;
    const int hi = l >> 4;
    const int wr = w >> 1;       // 0..3 quadrant row
    const int wc = w & 1;        // 0..1 quadrant col
    const int L = blockIdx.x;
    const int c = L & 7;
    const int t = L >> 3;            // 0..95
    const int by = c * 4 + (t & 3);  // 0..31
    const int bxs = t >> 2;          // 0..23
    const int wsel = bxs >> 3;       // 0..2
    const int bx = bxs & 7;          // 0..7
    const int m0 = by * 256;
    const int n0 = bx * 128;

    const u16* W = whb + (size_t)wsel * D_ * D_;
    const float* bias = wsel == 0 ? bq : wsel == 1 ? bk : bv;

    auto stage = [&](int k0, int buf) {
#pragma unroll
        for (int i = 0; i < 2; ++i) {       // A: 1024 slots / 512 thr
            const int p = 512 * i + tid;
            const int row = p >> 2;          // 0..255
            const int ps = p & 3;
            const int sl = ps ^ ((row + (row >> 2)) & 3);
            const int lb = buf * 8192 + (512 * i + 64 * w) * 8;
            gl16(xh + (size_t)(m0 + row) * D_ + k0 + 8 * sl, &sA[lb]);
        }
        {                                    // B: 512 slots / 512 thr
            const int p = tid;
            const int row = p >> 2;          // 0..127
            const int ps = p & 3;
            const int sl = ps ^ ((row + (row >> 2)) & 3);
            const int lb = buf * 4096 + (64 * w) * 8;
            gl16(W + (size_t)(n0 + row) * D_ + k0 + 8 * sl, &sB[lb]);
        }
    };

    const f32x4 z4 = {0.f, 0.f, 0.f, 0.f};
    f32x4 acc[4][4];
#pragma unroll
    for (int i = 0; i < 4; ++i)
#pragma unroll
        for (int j = 0; j < 4; ++j) acc[i][j] = z4;

    stage(0, 0);
    for (int k0 = 0; k0 < D_; k0 += 32) {
        const int cur = (k0 >> 5) & 1;
        __syncthreads();  // drains prefetched loads; closes prev reads
        if (k0 + 32 < D_) stage(k0 + 32, cur ^ 1);

        bf16x8 ah[4], bh[4];
#pragma unroll
        for (int mi = 0; mi < 4; ++mi) {
            const int r = wr * 64 + mi * 16 + lo;
            const int sl = hi ^ ((r + (r >> 2)) & 3);
            ah[mi] = *(const bf16x8*)&sA[cur * 8192 + r * 32 + sl * 8];
        }
#pragma unroll
        for (int nj = 0; nj < 4; ++nj) {
            const int r = wc * 64 + nj * 16 + lo;
            const int sl = hi ^ ((r + (r >> 2)) & 3);
            bh[nj] = *(const bf16x8*)&sB[cur * 4096 + r * 32 + sl * 8];
        }
#pragma unroll
        for (int mi = 0; mi < 4; ++mi)
#pragma unroll
            for (int nj = 0; nj < 4; ++nj)
                acc[mi][nj] = __builtin_amdgcn_mfma_f32_16x16x32_bf16(
                    ah[mi], bh[nj], acc[mi][nj], 0, 0, 0);
    }

    float bv_[4];
#pragma unroll
    for (int nj = 0; nj < 4; ++nj) bv_[nj] = bias[n0 + wc * 64 + nj * 16 + lo];

#pragma unroll
    for (int mi = 0; mi < 4; ++mi)
#pragma unroll
        for (int nj = 0; nj < 4; ++nj)
#pragma unroll
            for (int r = 0; r < 4; ++r) {
                const float v = acc[mi][nj][r] + bv_[nj];
                const int cm = m0 + wr * 64 + mi * 16 + hi * 4 + r;
                const int cn = n0 + wc * 64 + nj * 16 + lo;
                const int b = cm >> 11, s = cm & (S_ - 1);
                const int h = cn >> 6, d = cn & 63;
                if (wsel == 0)  // fold 0.125 * log2(e) for log2-domain softmax
                    qb[(((size_t)b * H_ + h) * S_ + s) * DH + d] =
                        f2bf(v * 0.18033688011112042f);
                else if (wsel == 1)
                    kb[(((size_t)b * H_ + h) * S_ + s) * DH + d] = f2bf(v);
                else
                    vt[(((size_t)b * H_ + h) * DH + d) * S_ + s] = f2bf(v);
            }
}

// ---------------------------------------------------------------------------
// Final GEMM: out = ctx @ wo^T + bo, 1-PASS bf16, fp32 output.
// Error analysis: dropping split-bf16 adds ~2e-5 sigma (max ~1e-4) vs the
// 4.88e-4 P-rounding-dominated absmax and 1.83e-3 threshold (round-5's QKV
// argument, validated). Same dbuf structure (1 barrier/K-step), LDS 32KB.
// ---------------------------------------------------------------------------
__global__ __launch_bounds__(256) void gemm_out1(const u16* __restrict__ Ab,
                                                 const u16* __restrict__ Wb,
                                                 const float* __restrict__ bias,
                                                 float* __restrict__ Cout) {
    __shared__ __align__(16) u16 sA[8192];
    __shared__ __align__(16) u16 sB[8192];

    const int tid = threadIdx.x;
    const int l = tid & 63;
    const int w = tid >> 6;
    const int lo = l & 15;
    const int hi = l >> 4;
    const int wr = w >> 1;
    const int wc = w & 1;
    const int L = blockIdx.x;
    const int c = L & 7;
    const int t = L >> 3;
    const int by = c * 8 + (t >> 3);
    const int bx = t & 7;
    const int m0 = by * 128;
    const int n0 = bx * 128;

    auto stage = [&](int k0, int half) {
#pragma unroll
        for (int i = 0; i < 2; ++i) {
            const int p = 256 * i + tid;
            const int row = p >> 2;
            const int ps = p & 3;
            const int sl = ps ^ ((row + (row >> 2)) & 3);
            const int lb = half * 4096 + (256 * i + 64 * w) * 8;
            gl16(Ab + (size_t)(m0 + row) * D_ + k0 + 8 * sl, &sA[lb]);
            gl16(Wb + (size_t)(n0 + row) * D_ + k0 + 8 * sl, &sB[lb]);
        }
    };

    const f32x4 z4 = {0.f, 0.f, 0.f, 0.f};
    f32x4 acc[4][4];
#pragma unroll
    for (int i = 0; i < 4; ++i)
#pragma unroll
        for (int j = 0; j < 4; ++j) acc[i][j] = z4;

    stage(0, 0);
    for (int k0 = 0; k0 < D_; k0 += 32) {
        const int cur = (k0 >> 5) & 1;
        __syncthreads();  // drains prefetched loads; closes prev reads
        if (k0 + 32 < D_) stage(k0 + 32, cur ^ 1);
        const int bufo = cur * 4096;

        bf16x8 ah[4], bh[4];
#pragma unroll
        for (int mi = 0; mi < 4; ++mi) {
            const int r = wr * 64 + mi * 16 + lo;
            const int sl = hi ^ ((r + (r >> 2)) & 3);
            ah[mi] = *(const bf16x8*)&sA[bufo + r * 32 + sl * 8];
        }
#pragma unroll
        for (int nj = 0; nj < 4; ++nj) {
            const int r = wc * 64 + nj * 16 + lo;
            const int sl = hi ^ ((r + (r >> 2)) & 3);
            bh[nj] = *(const bf16x8*)&sB[bufo + r * 32 + sl * 8];
        }
#pragma unroll
        for (int mi = 0; mi < 4; ++mi)
#pragma unroll
            for (int nj = 0; nj < 4; ++nj)
                acc[mi][nj] = __builtin_amdgcn_mfma_f32_16x16x32_bf16(
                    ah[mi], bh[nj], acc[mi][nj], 0, 0, 0);
    }

    float bv_[4];
#pragma unroll
    for (int nj = 0; nj < 4; ++nj) bv_[nj] = bias[n0 + wc * 64 + nj * 16 + lo];

#pragma unroll
    for (int mi = 0; mi < 4; ++mi)
#pragma unroll
        for (int nj = 0; nj < 4; ++nj)
#pragma unroll
            for (int r = 0; r < 4; ++r) {
                const int cm = m0 + wr * 64 + mi * 16 + hi * 4 + r;
                const int cn = n0 + wc * 64 + nj * 16 + lo;
                Cout[(size_t)cm * D_ + cn] = acc[mi][nj][r] + bv_[nj];
            }
}

// ---------------------------------------------------------------------------
// MFMA flash attention, fixed-max softmax, in-register P via cvt_pk+permlane
// (T12). Round-8/10 proven version. Epilogue now writes single bf16 ctx
// (1-pass output GEMM needs no hi/lo split). LDS 32KB, 4 blocks/CU.
// ---------------------------------------------------------------------------
__global__ __launch_bounds__(256, 4) void attn6(const u16* __restrict__ Qb,
                                                const u16* __restrict__ Kb,
                                                const u16* __restrict__ Vtg,
                                                u16* __restrict__ chi) {
    __shared__ __align__(16) u16 KsA[2 * 4096];  // [buf][kv 64][d 64] swizzled
    __shared__ __align__(16) u16 VsA[2 * 4096];  // [buf][d 64][kv 64] swizzled

    const int tid = threadIdx.x;
    const int l = tid & 63;
    const int w = tid >> 6;
    const int lo = l & 15;
    const int hi = l >> 4;
    const int L = blockIdx.x;
    const int c = L & 7;
    const int t = L >> 3;             // 0..127
    const int bh = c * 8 + (t >> 4);  // 0..63
    const int s0 = (t & 15) * 128;
    const size_t base = (size_t)bh * S_ * DH;

    const int sp0 = tid;
    const int srow0 = sp0 >> 3, ssl0 = (sp0 & 7) ^ (srow0 & 7);
    const int sp1 = 256 + tid;
    const int srow1 = sp1 >> 3, ssl1 = (sp1 & 7) ^ (srow1 & 7);
    const int lb0 = (64 * w) * 8;
    const int lb1 = (256 + 64 * w) * 8;

    // Q fragments, 2 q-halves (pre-scaled by 0.125*log2e in the QKV epilogue)
    bf16x8 qa[2][2];
#pragma unroll
    for (int qh = 0; qh < 2; ++qh) {
        const u16* qp = Qb + base + (size_t)(s0 + w * 32 + qh * 16 + lo) * DH;
        qa[qh][0] = *(const bf16x8*)(qp + hi * 8);
        qa[qh][1] = *(const bf16x8*)(qp + hi * 8 + 32);
    }

    const f32x4 zero4 = {0.f, 0.f, 0.f, 0.f};
    f32x4 acc[2][4];
    f32x4 acc_l[2] = {zero4, zero4};
#pragma unroll
    for (int qh = 0; qh < 2; ++qh)
#pragma unroll
        for (int g = 0; g < 4; ++g) acc[qh][g] = zero4;

    const short onebf = (short)0x3F80;  // bf16 1.0
    const bf16x8 ones = {onebf, onebf, onebf, onebf, onebf, onebf, onebf, onebf};

#define STAGE(KT, HALF)                                                        \
    do {                                                                       \
        const size_t kbase = base + (size_t)(KT) * 64 * DH;                    \
        const size_t vbase = base + (size_t)(KT) * 64;                         \
        gl16(Kb + kbase + (size_t)srow0 * DH + 8 * ssl0, &KsA[(HALF)*4096 + lb0]); \
        gl16(Vtg + vbase + (size_t)srow0 * S_ + 8 * ssl0, &VsA[(HALF)*4096 + lb0]); \
        gl16(Kb + kbase + (size_t)srow1 * DH + 8 * ssl1, &KsA[(HALF)*4096 + lb1]); \
        gl16(Vtg + vbase + (size_t)srow1 * S_ + 8 * ssl1, &VsA[(HALF)*4096 + lb1]); \
    } while (0)

    STAGE(0, 0);

    for (int kt = 0; kt < S_ / 64; ++kt) {
        const int cur = kt & 1;
        __syncthreads();  // drains vmcnt -> tile kt staged; closes prev reads
        if (kt + 1 < S_ / 64) STAGE(kt + 1, cur ^ 1);
        const u16* Ks = &KsA[cur * 4096];
        const u16* Vs = &VsA[cur * 4096];

        // --- QK^T (swapped), K-frag shared across both q-halves
        f32x4 sc[2][4];
#pragma unroll
        for (int qh = 0; qh < 2; ++qh)
#pragma unroll
            for (int f = 0; f < 4; ++f) sc[qh][f] = zero4;
        __builtin_amdgcn_s_setprio(1);
#pragma unroll
        for (int f = 0; f < 4; ++f) {
            const int kr = lo + 16 * f;
            const int ksw = (kr & 7) << 3;
#pragma unroll
            for (int ks = 0; ks < 2; ++ks) {
                bf16x8 kf = *(const bf16x8*)&Ks[kr * 64 + ((hi * 8 + 32 * ks) ^ ksw)];
                sc[0][f] = __builtin_amdgcn_mfma_f32_16x16x32_bf16(kf, qa[0][ks], sc[0][f], 0, 0, 0);
                sc[1][f] = __builtin_amdgcn_mfma_f32_16x16x32_bf16(kf, qa[1][ks], sc[1][f], 0, 0, 0);
            }
        }
        __builtin_amdgcn_s_setprio(0);

        // --- p = exp2(sc); pack + permlane into PV A-fragments (no LDS)
        bf16x8 pa[2][2];
#pragma unroll
        for (int qh = 0; qh < 2; ++qh) {
            u32 T[2][4];
#pragma unroll
            for (int ks = 0; ks < 2; ++ks)
#pragma unroll
                for (int cc = 0; cc < 2; ++cc) {
                    u32 X = cvtpk(fexp2(sc[qh][2 * ks][2 * cc]),
                                  fexp2(sc[qh][2 * ks][2 * cc + 1]));
                    u32 Y = cvtpk(fexp2(sc[qh][2 * ks + 1][2 * cc]),
                                  fexp2(sc[qh][2 * ks + 1][2 * cc + 1]));
                    pswap32(X, Y);
                    pswap16(X, Y);
                    T[ks][cc] = X;
                    T[ks][2 + cc] = Y;
                }
#pragma unroll
            for (int ks = 0; ks < 2; ++ks) {
                u32x4 word = {T[ks][0], T[ks][1], T[ks][2], T[ks][3]};
                pa[qh][ks] = __builtin_bit_cast(bf16x8, word);
            }
        }

        // --- PV (swapped) + MFMA row-sum; V-frag shared across q-halves
        __builtin_amdgcn_s_setprio(1);
        acc_l[0] = __builtin_amdgcn_mfma_f32_16x16x32_bf16(ones, pa[0][0], acc_l[0], 0, 0, 0);
        acc_l[0] = __builtin_amdgcn_mfma_f32_16x16x32_bf16(ones, pa[0][1], acc_l[0], 0, 0, 0);
        acc_l[1] = __builtin_amdgcn_mfma_f32_16x16x32_bf16(ones, pa[1][0], acc_l[1], 0, 0, 0);
        acc_l[1] = __builtin_amdgcn_mfma_f32_16x16x32_bf16(ones, pa[1][1], acc_l[1], 0, 0, 0);
#pragma unroll
        for (int g = 0; g < 4; ++g) {
            const int vr = lo + 16 * g;
            const int vsw = (vr & 7) << 3;
#pragma unroll
            for (int ks = 0; ks < 2; ++ks) {
                bf16x8 vf = *(const bf16x8*)&Vs[vr * 64 + ((hi * 8 + 32 * ks) ^ vsw)];
                acc[0][g] = __builtin_amdgcn_mfma_f32_16x16x32_bf16(vf, pa[0][ks], acc[0][g], 0, 0, 0);
                acc[1][g] = __builtin_amdgcn_mfma_f32_16x16x32_bf16(vf, pa[1][ks], acc[1][g], 0, 0, 0);
            }
        }
        __builtin_amdgcn_s_setprio(0);
    }
#undef STAGE

    // epilogue: O[q][d] / l, single bf16 ctx write
    const int b = bh >> 4;
    const int h = bh & 15;
#pragma unroll
    for (int qh = 0; qh < 2; ++qh) {
        const float inv = 1.f / acc_l[qh][0];
        const int row = s0 + w * 32 + qh * 16 + lo;
#pragma unroll
        for (int g = 0; g < 4; ++g) {
            u16x4 hh;
#pragma unroll
            for (int r = 0; r < 4; ++r) hh[r] = f2bf_hw(acc[qh][g][r] * inv);
            const size_t off = ((size_t)b * S_ + row) * D_ + h * 64 + 16 * g + hi * 4;
            *(u16x4*)&chi[off] = hh;
        }
    }
}

// ---------------------------------------------------------------------------
extern "C" void kernel_launch(void* const* d_in, const int* in_sizes, int n_in,
                              void* d_out, int out_size, void* d_ws, size_t ws_size,
                              hipStream_t stream) {
    const float* x  = (const float*)d_in[0];
    const float* wq = (const float*)d_in[1];
    const float* bq = (const float*)d_in[2];
    const float* wk = (const float*)d_in[3];
    const float* bk = (const float*)d_in[4];
    const float* wv = (const float*)d_in[5];
    const float* bv = (const float*)d_in[6];
    const float* wo = (const float*)d_in[7];
    const float* bo = (const float*)d_in[8];
    float* out = (float*)d_out;

    const size_t MD = (size_t)M_ * D_;  // 8388608
    const size_t WD = (size_t)D_ * D_;  // 1048576
    u16* ws = (u16*)d_ws;
    u16* xh  = ws;             // MD
    u16* wh  = xh + MD;        // 3*WD (wq,wk,wv bf16)
    u16* woh = wh + 3 * WD;    // WD
    u16* qb  = woh + WD;       // MD
    u16* kb  = qb + MD;        // MD
    u16* vt  = kb + MD;        // MD
    u16* chi = xh;             // alias: x consumed by QKV GEMM before attn writes

    dim3 blk(256);
    // float4 work items: x 2M + 3 W casts 768K + wo cast 256K = 3145728
    prep<<<dim3(12288), blk, 0, stream>>>(x, wq, wk, wv, wo, xh, wh, woh);
    gemm_qkv<<<dim3(768), dim3(512), 0, stream>>>(xh, wh, bq, bk, bv, qb, kb, vt);
    attn6<<<dim3(1024), blk, 0, stream>>>(qb, kb, vt, chi);
    gemm_out1<<<dim3(512), blk, 0, stream>>>(chi, woh, bo, out);
}

// Round 16
// 180.242 us; speedup vs baseline: 1.9929x; 1.0400x over previous
//
#include <hip/hip_runtime.h>
#include <hip/hip_bf16.h>

#define B_  4
#define S_  2048
#define D_  1024
#define H_  16
#define DH  64
#define M_  (B_ * S_)   // 8192

typedef unsigned short u16;
typedef unsigned int u32;
typedef __attribute__((ext_vector_type(8))) short bf16x8;
typedef __attribute__((ext_vector_type(4))) float f32x4;
typedef __attribute__((ext_vector_type(4))) unsigned short u16x4;
typedef __attribute__((ext_vector_type(4))) unsigned int u32x4;

static __device__ __forceinline__ u16 f2bf(float x) {
    union { float f; unsigned u; } c;
    c.f = x;
    const unsigned u = c.u;
    return (u16)((u + 0x7FFFu + ((u >> 16) & 1u)) >> 16);
}
static __device__ __forceinline__ float bf2f(u16 h) {
    union { unsigned u; float f; } c;
    c.u = ((unsigned)h) << 16;
    return c.f;
}
#ifdef __BF16_MANT_DIG__
static __device__ __forceinline__ u16 f2bf_hw(float x) {
    __bf16 b = (__bf16)x;
    return __builtin_bit_cast(u16, b);
}
#else
#define f2bf_hw f2bf
#endif
#if __has_builtin(__builtin_amdgcn_exp2f)
#define fexp2 __builtin_amdgcn_exp2f
#else
#define fexp2 exp2f
#endif
// async 16B global->LDS (LDS dest = wave-uniform base + lane*16)
static __device__ __forceinline__ void gl16(const u16* g, u16* l) {
    __builtin_amdgcn_global_load_lds(
        (const __attribute__((address_space(1))) unsigned int*)g,
        (__attribute__((address_space(3))) unsigned int*)l, 16, 0, 0);
}
// v_cvt_pk_bf16_f32: dst.lo16=bf16(a), dst.hi16=bf16(b)
static __device__ __forceinline__ u32 cvtpk(float a, float b) {
    u32 r;
    asm("v_cvt_pk_bf16_f32 %0, %1, %2" : "=v"(r) : "v"(a), "v"(b));
    return r;
}

// ---------------------------------------------------------------------------
// Fused prep: cast x,wq,wk,wv,wo -> bf16. One launch.
// ---------------------------------------------------------------------------
__global__ __launch_bounds__(256) void prep(const float* __restrict__ x,
                                            const float* __restrict__ wq,
                                            const float* __restrict__ wk,
                                            const float* __restrict__ wv,
                                            const float* __restrict__ wo,
                                            u16* __restrict__ xh,
                                            u16* __restrict__ wh,   // 3 blocks
                                            u16* __restrict__ woh) {
    const size_t NX = (size_t)M_ * D_ / 4;  // 2097152
    const size_t NW = (size_t)D_ * D_ / 4;  // 262144
    const size_t i = (size_t)blockIdx.x * 256 + threadIdx.x;
    if (i < NX) {
        float4 v = ((const float4*)x)[i];
        u16x4 h;
        h[0] = f2bf_hw(v.x); h[1] = f2bf_hw(v.y);
        h[2] = f2bf_hw(v.z); h[3] = f2bf_hw(v.w);
        ((u16x4*)xh)[i] = h;
    } else if (i < NX + 3 * NW) {
        const size_t j = i - NX;
        const int sel = (int)(j / NW);
        const size_t k = j - (size_t)sel * NW;
        const float* src = sel == 0 ? wq : sel == 1 ? wk : wv;
        float4 v = ((const float4*)src)[k];
        u16x4 h;
        h[0] = f2bf_hw(v.x); h[1] = f2bf_hw(v.y);
        h[2] = f2bf_hw(v.z); h[3] = f2bf_hw(v.w);
        ((u16x4*)(wh + (size_t)sel * D_ * D_))[k] = h;
    } else {
        const size_t k = i - NX - 3 * NW;
        float4 v = ((const float4*)wo)[k];
        u16x4 h;
        h[0] = f2bf_hw(v.x); h[1] = f2bf_hw(v.y);
        h[2] = f2bf_hw(v.z); h[3] = f2bf_hw(v.w);
        ((u16x4*)woh)[k] = h;
    }
}

// ---------------------------------------------------------------------------
// Merged QKV GEMM: {Q,K,V} = x @ W{q,k,v}^T + b, 1-pass bf16, double-buffered
// (1 barrier/K-step). 256x128 tile, 8 waves (512 thr, 4x2 quadrants).
// Grid 768, XCD-chunked, W-tile-major within XCD. UNCHANGED from round 15.
// ---------------------------------------------------------------------------
__global__ __launch_bounds__(512) void gemm_qkv(const u16* __restrict__ xh,
                                                const u16* __restrict__ whb,
                                                const float* __restrict__ bq,
                                                const float* __restrict__ bk,
                                                const float* __restrict__ bv,
                                                u16* __restrict__ qb,
                                                u16* __restrict__ kb,
                                                u16* __restrict__ vt) {
    __shared__ __align__(16) u16 sA[2 * 8192];  // [buf][256 rows][32 cols]
    __shared__ __align__(16) u16 sB[2 * 4096];  // [buf][128 rows][32 cols]

    const int tid = threadIdx.x;
    const int l = tid & 63;
    const int w = tid >> 6;      // 0..7
    const int lo = l & 15;
    const int hi = l >> 4;
    const int wr = w >> 1;       // 0..3 quadrant row
    const int wc = w & 1;        // 0..1 quadrant col
    const int L = blockIdx.x;
    const int c = L & 7;
    const int t = L >> 3;            // 0..95
    const int by = c * 4 + (t & 3);  // 0..31
    const int bxs = t >> 2;          // 0..23
    const int wsel = bxs >> 3;       // 0..2
    const int bx = bxs & 7;          // 0..7
    const int m0 = by * 256;
    const int n0 = bx * 128;

    const u16* W = whb + (size_t)wsel * D_ * D_;
    const float* bias = wsel == 0 ? bq : wsel == 1 ? bk : bv;

    auto stage = [&](int k0, int buf) {
#pragma unroll
        for (int i = 0; i < 2; ++i) {       // A: 1024 slots / 512 thr
            const int p = 512 * i + tid;
            const int row = p >> 2;          // 0..255
            const int ps = p & 3;
            const int sl = ps ^ ((row + (row >> 2)) & 3);
            const int lb = buf * 8192 + (512 * i + 64 * w) * 8;
            gl16(xh + (size_t)(m0 + row) * D_ + k0 + 8 * sl, &sA[lb]);
        }
        {                                    // B: 512 slots / 512 thr
            const int p = tid;
            const int row = p >> 2;          // 0..127
            const int ps = p & 3;
            const int sl = ps ^ ((row + (row >> 2)) & 3);
            const int lb = buf * 4096 + (64 * w) * 8;
            gl16(W + (size_t)(n0 + row) * D_ + k0 + 8 * sl, &sB[lb]);
        }
    };

    const f32x4 z4 = {0.f, 0.f, 0.f, 0.f};
    f32x4 acc[4][4];
#pragma unroll
    for (int i = 0; i < 4; ++i)
#pragma unroll
        for (int j = 0; j < 4; ++j) acc[i][j] = z4;

    stage(0, 0);
    for (int k0 = 0; k0 < D_; k0 += 32) {
        const int cur = (k0 >> 5) & 1;
        __syncthreads();  // drains prefetched loads; closes prev reads
        if (k0 + 32 < D_) stage(k0 + 32, cur ^ 1);

        bf16x8 ah[4], bh[4];
#pragma unroll
        for (int mi = 0; mi < 4; ++mi) {
            const int r = wr * 64 + mi * 16 + lo;
            const int sl = hi ^ ((r + (r >> 2)) & 3);
            ah[mi] = *(const bf16x8*)&sA[cur * 8192 + r * 32 + sl * 8];
        }
#pragma unroll
        for (int nj = 0; nj < 4; ++nj) {
            const int r = wc * 64 + nj * 16 + lo;
            const int sl = hi ^ ((r + (r >> 2)) & 3);
            bh[nj] = *(const bf16x8*)&sB[cur * 4096 + r * 32 + sl * 8];
        }
#pragma unroll
        for (int mi = 0; mi < 4; ++mi)
#pragma unroll
            for (int nj = 0; nj < 4; ++nj)
                acc[mi][nj] = __builtin_amdgcn_mfma_f32_16x16x32_bf16(
                    ah[mi], bh[nj], acc[mi][nj], 0, 0, 0);
    }

    float bv_[4];
#pragma unroll
    for (int nj = 0; nj < 4; ++nj) bv_[nj] = bias[n0 + wc * 64 + nj * 16 + lo];

#pragma unroll
    for (int mi = 0; mi < 4; ++mi)
#pragma unroll
        for (int nj = 0; nj < 4; ++nj)
#pragma unroll
            for (int r = 0; r < 4; ++r) {
                const float v = acc[mi][nj][r] + bv_[nj];
                const int cm = m0 + wr * 64 + mi * 16 + hi * 4 + r;
                const int cn = n0 + wc * 64 + nj * 16 + lo;
                const int b = cm >> 11, s = cm & (S_ - 1);
                const int h = cn >> 6, d = cn & 63;
                if (wsel == 0)  // fold 0.125 * log2(e) for log2-domain softmax
                    qb[(((size_t)b * H_ + h) * S_ + s) * DH + d] =
                        f2bf(v * 0.18033688011112042f);
                else if (wsel == 1)
                    kb[(((size_t)b * H_ + h) * S_ + s) * DH + d] = f2bf(v);
                else
                    vt[(((size_t)b * H_ + h) * DH + d) * S_ + s] = f2bf(v);
            }
}

// ---------------------------------------------------------------------------
// Final GEMM: out = ctx @ wo^T + bo, 1-pass bf16, fp32 output.
// Double-buffered (1 barrier/K-step), LDS 32KB. UNCHANGED from round 15.
// ---------------------------------------------------------------------------
__global__ __launch_bounds__(256) void gemm_out1(const u16* __restrict__ Ab,
                                                 const u16* __restrict__ Wb,
                                                 const float* __restrict__ bias,
                                                 float* __restrict__ Cout) {
    __shared__ __align__(16) u16 sA[8192];
    __shared__ __align__(16) u16 sB[8192];

    const int tid = threadIdx.x;
    const int l = tid & 63;
    const int w = tid >> 6;
    const int lo = l & 15;
    const int hi = l >> 4;
    const int wr = w >> 1;
    const int wc = w & 1;
    const int L = blockIdx.x;
    const int c = L & 7;
    const int t = L >> 3;
    const int by = c * 8 + (t >> 3);
    const int bx = t & 7;
    const int m0 = by * 128;
    const int n0 = bx * 128;

    auto stage = [&](int k0, int half) {
#pragma unroll
        for (int i = 0; i < 2; ++i) {
            const int p = 256 * i + tid;
            const int row = p >> 2;
            const int ps = p & 3;
            const int sl = ps ^ ((row + (row >> 2)) & 3);
            const int lb = half * 4096 + (256 * i + 64 * w) * 8;
            gl16(Ab + (size_t)(m0 + row) * D_ + k0 + 8 * sl, &sA[lb]);
            gl16(Wb + (size_t)(n0 + row) * D_ + k0 + 8 * sl, &sB[lb]);
        }
    };

    const f32x4 z4 = {0.f, 0.f, 0.f, 0.f};
    f32x4 acc[4][4];
#pragma unroll
    for (int i = 0; i < 4; ++i)
#pragma unroll
        for (int j = 0; j < 4; ++j) acc[i][j] = z4;

    stage(0, 0);
    for (int k0 = 0; k0 < D_; k0 += 32) {
        const int cur = (k0 >> 5) & 1;
        __syncthreads();  // drains prefetched loads; closes prev reads
        if (k0 + 32 < D_) stage(k0 + 32, cur ^ 1);
        const int bufo = cur * 4096;

        bf16x8 ah[4], bh[4];
#pragma unroll
        for (int mi = 0; mi < 4; ++mi) {
            const int r = wr * 64 + mi * 16 + lo;
            const int sl = hi ^ ((r + (r >> 2)) & 3);
            ah[mi] = *(const bf16x8*)&sA[bufo + r * 32 + sl * 8];
        }
#pragma unroll
        for (int nj = 0; nj < 4; ++nj) {
            const int r = wc * 64 + nj * 16 + lo;
            const int sl = hi ^ ((r + (r >> 2)) & 3);
            bh[nj] = *(const bf16x8*)&sB[bufo + r * 32 + sl * 8];
        }
#pragma unroll
        for (int mi = 0; mi < 4; ++mi)
#pragma unroll
            for (int nj = 0; nj < 4; ++nj)
                acc[mi][nj] = __builtin_amdgcn_mfma_f32_16x16x32_bf16(
                    ah[mi], bh[nj], acc[mi][nj], 0, 0, 0);
    }

    float bv_[4];
#pragma unroll
    for (int nj = 0; nj < 4; ++nj) bv_[nj] = bias[n0 + wc * 64 + nj * 16 + lo];

#pragma unroll
    for (int mi = 0; mi < 4; ++mi)
#pragma unroll
        for (int nj = 0; nj < 4; ++nj)
#pragma unroll
            for (int r = 0; r < 4; ++r) {
                const int cm = m0 + wr * 64 + mi * 16 + hi * 4 + r;
                const int cn = n0 + wc * 64 + nj * 16 + lo;
                Cout[(size_t)cm * D_ + cn] = acc[mi][nj][r] + bv_[nj];
            }
}

// ---------------------------------------------------------------------------
// MFMA flash attention v10 = round-15 attn6 with the cross-lane P transpose
// ELIMINATED via K-row permutation at stage time:
//   LDS A-row m holds global K row g(m), g(m)=32*(idx>>3)+8*((m>>2)&3)+(idx&7),
//   idx=4*(m>>4)+(m&3). Then sc[f][r] on lane (lo,hi) is the score vs
//   kv = 32ks+8hi+j with 8ks+j = 4f+r — exactly the PV A-fragment layout, so
//   pa assembly is cvtpk-only (16 permlane instructions/tile deleted, and the
//   exp2->cvtpk->swap serial chain shortened). Values bit-identical: PV and
//   ones-rowsum are order-correct by construction. Source-row permutation only
//   (LDS dest linear, col-XOR swizzle unchanged — keyed on LDS row index).
// ---------------------------------------------------------------------------
__global__ __launch_bounds__(256, 4) void attn6(const u16* __restrict__ Qb,
                                                const u16* __restrict__ Kb,
                                                const u16* __restrict__ Vtg,
                                                u16* __restrict__ chi) {
    __shared__ __align__(16) u16 KsA[2 * 4096];  // [buf][kv-pos 64][d 64] swizzled
    __shared__ __align__(16) u16 VsA[2 * 4096];  // [buf][d 64][kv 64] swizzled

    const int tid = threadIdx.x;
    const int l = tid & 63;
    const int w = tid >> 6;
    const int lo = l & 15;
    const int hi = l >> 4;
    const int L = blockIdx.x;
    const int c = L & 7;
    const int t = L >> 3;             // 0..127
    const int bh = c * 8 + (t >> 4);  // 0..63
    const int s0 = (t & 15) * 128;
    const size_t base = (size_t)bh * S_ * DH;

    const int sp0 = tid;
    const int srow0 = sp0 >> 3, ssl0 = (sp0 & 7) ^ (srow0 & 7);
    const int sp1 = 256 + tid;
    const int srow1 = sp1 >> 3, ssl1 = (sp1 & 7) ^ (srow1 & 7);
    const int lb0 = (64 * w) * 8;
    const int lb1 = (256 + 64 * w) * 8;
    // K source-row permutation g: LDS A-row m <- global K row g(m)
    auto gperm = [](int m) {
        const int idx = 4 * (m >> 4) + (m & 3);
        return 32 * (idx >> 3) + 8 * ((m >> 2) & 3) + (idx & 7);
    };
    const int gk0 = gperm(srow0);
    const int gk1 = gperm(srow1);

    // Q fragments, 2 q-halves (pre-scaled by 0.125*log2e in the QKV epilogue)
    bf16x8 qa[2][2];
#pragma unroll
    for (int qh = 0; qh < 2; ++qh) {
        const u16* qp = Qb + base + (size_t)(s0 + w * 32 + qh * 16 + lo) * DH;
        qa[qh][0] = *(const bf16x8*)(qp + hi * 8);
        qa[qh][1] = *(const bf16x8*)(qp + hi * 8 + 32);
    }

    const f32x4 zero4 = {0.f, 0.f, 0.f, 0.f};
    f32x4 acc[2][4];
    f32x4 acc_l[2] = {zero4, zero4};
#pragma unroll
    for (int qh = 0; qh < 2; ++qh)
#pragma unroll
        for (int g = 0; g < 4; ++g) acc[qh][g] = zero4;

    const short onebf = (short)0x3F80;  // bf16 1.0
    const bf16x8 ones = {onebf, onebf, onebf, onebf, onebf, onebf, onebf, onebf};

#define STAGE(KT, HALF)                                                        \
    do {                                                                       \
        const size_t kbase = base + (size_t)(KT) * 64 * DH;                    \
        const size_t vbase = base + (size_t)(KT) * 64;                         \
        gl16(Kb + kbase + (size_t)gk0 * DH + 8 * ssl0, &KsA[(HALF)*4096 + lb0]); \
        gl16(Vtg + vbase + (size_t)srow0 * S_ + 8 * ssl0, &VsA[(HALF)*4096 + lb0]); \
        gl16(Kb + kbase + (size_t)gk1 * DH + 8 * ssl1, &KsA[(HALF)*4096 + lb1]); \
        gl16(Vtg + vbase + (size_t)srow1 * S_ + 8 * ssl1, &VsA[(HALF)*4096 + lb1]); \
    } while (0)

    STAGE(0, 0);

    for (int kt = 0; kt < S_ / 64; ++kt) {
        const int cur = kt & 1;
        __syncthreads();  // drains vmcnt -> tile kt staged; closes prev reads
        if (kt + 1 < S_ / 64) STAGE(kt + 1, cur ^ 1);
        const u16* Ks = &KsA[cur * 4096];
        const u16* Vs = &VsA[cur * 4096];

        // --- QK^T (swapped), K-frag shared across both q-halves
        f32x4 sc[2][4];
#pragma unroll
        for (int qh = 0; qh < 2; ++qh)
#pragma unroll
            for (int f = 0; f < 4; ++f) sc[qh][f] = zero4;
        __builtin_amdgcn_s_setprio(1);
#pragma unroll
        for (int f = 0; f < 4; ++f) {
            const int kr = lo + 16 * f;
            const int ksw = (kr & 7) << 3;
#pragma unroll
            for (int ks = 0; ks < 2; ++ks) {
                bf16x8 kf = *(const bf16x8*)&Ks[kr * 64 + ((hi * 8 + 32 * ks) ^ ksw)];
                sc[0][f] = __builtin_amdgcn_mfma_f32_16x16x32_bf16(kf, qa[0][ks], sc[0][f], 0, 0, 0);
                sc[1][f] = __builtin_amdgcn_mfma_f32_16x16x32_bf16(kf, qa[1][ks], sc[1][f], 0, 0, 0);
            }
        }
        __builtin_amdgcn_s_setprio(0);

        // --- p = exp2(sc); cvtpk-only PV A-fragment assembly (no cross-lane:
        //     the K-row permutation pre-arranged sc into PV layout)
        bf16x8 pa[2][2];
#pragma unroll
        for (int qh = 0; qh < 2; ++qh)
#pragma unroll
            for (int ks = 0; ks < 2; ++ks) {
                u32x4 word;
#pragma unroll
                for (int cc = 0; cc < 4; ++cc) {
                    const int f = ks * 2 + (cc >> 1);
                    const int r0 = (cc & 1) * 2;
                    word[cc] = cvtpk(fexp2(sc[qh][f][r0]), fexp2(sc[qh][f][r0 + 1]));
                }
                pa[qh][ks] = __builtin_bit_cast(bf16x8, word);
            }

        // --- PV (swapped) + MFMA row-sum; V-frag shared across q-halves
        __builtin_amdgcn_s_setprio(1);
        acc_l[0] = __builtin_amdgcn_mfma_f32_16x16x32_bf16(ones, pa[0][0], acc_l[0], 0, 0, 0);
        acc_l[0] = __builtin_amdgcn_mfma_f32_16x16x32_bf16(ones, pa[0][1], acc_l[0], 0, 0, 0);
        acc_l[1] = __builtin_amdgcn_mfma_f32_16x16x32_bf16(ones, pa[1][0], acc_l[1], 0, 0, 0);
        acc_l[1] = __builtin_amdgcn_mfma_f32_16x16x32_bf16(ones, pa[1][1], acc_l[1], 0, 0, 0);
#pragma unroll
        for (int g = 0; g < 4; ++g) {
            const int vr = lo + 16 * g;
            const int vsw = (vr & 7) << 3;
#pragma unroll
            for (int ks = 0; ks < 2; ++ks) {
                bf16x8 vf = *(const bf16x8*)&Vs[vr * 64 + ((hi * 8 + 32 * ks) ^ vsw)];
                acc[0][g] = __builtin_amdgcn_mfma_f32_16x16x32_bf16(vf, pa[0][ks], acc[0][g], 0, 0, 0);
                acc[1][g] = __builtin_amdgcn_mfma_f32_16x16x32_bf16(vf, pa[1][ks], acc[1][g], 0, 0, 0);
            }
        }
        __builtin_amdgcn_s_setprio(0);
    }
#undef STAGE

    // epilogue: O[q][d] / l, single bf16 ctx write
    const int b = bh >> 4;
    const int h = bh & 15;
#pragma unroll
    for (int qh = 0; qh < 2; ++qh) {
        const float inv = 1.f / acc_l[qh][0];
        const int row = s0 + w * 32 + qh * 16 + lo;
#pragma unroll
        for (int g = 0; g < 4; ++g) {
            u16x4 hh;
#pragma unroll
            for (int r = 0; r < 4; ++r) hh[r] = f2bf_hw(acc[qh][g][r] * inv);
            const size_t off = ((size_t)b * S_ + row) * D_ + h * 64 + 16 * g + hi * 4;
            *(u16x4*)&chi[off] = hh;
        }
    }
}

// ---------------------------------------------------------------------------
extern "C" void kernel_launch(void* const* d_in, const int* in_sizes, int n_in,
                              void* d_out, int out_size, void* d_ws, size_t ws_size,
                              hipStream_t stream) {
    const float* x  = (const float*)d_in[0];
    const float* wq = (const float*)d_in[1];
    const float* bq = (const float*)d_in[2];
    const float* wk = (const float*)d_in[3];
    const float* bk = (const float*)d_in[4];
    const float* wv = (const float*)d_in[5];
    const float* bv = (const float*)d_in[6];
    const float* wo = (const float*)d_in[7];
    const float* bo = (const float*)d_in[8];
    float* out = (float*)d_out;

    const size_t MD = (size_t)M_ * D_;  // 8388608
    const size_t WD = (size_t)D_ * D_;  // 1048576
    u16* ws = (u16*)d_ws;
    u16* xh  = ws;             // MD
    u16* wh  = xh + MD;        // 3*WD (wq,wk,wv bf16)
    u16* woh = wh + 3 * WD;    // WD
    u16* qb  = woh + WD;       // MD
    u16* kb  = qb + MD;        // MD
    u16* vt  = kb + MD;        // MD
    u16* chi = xh;             // alias: x consumed by QKV GEMM before attn writes

    dim3 blk(256);
    // float4 work items: x 2M + 3 W casts 768K + wo cast 256K = 3145728
    prep<<<dim3(12288), blk, 0, stream>>>(x, wq, wk, wv, wo, xh, wh, woh);
    gemm_qkv<<<dim3(768), dim3(512), 0, stream>>>(xh, wh, bq, bk, bv, qb, kb, vt);
    attn6<<<dim3(1024), blk, 0, stream>>>(qb, kb, vt, chi);
    gemm_out1<<<dim3(512), blk, 0, stream>>>(chi, woh, bo, out);
}